// Round 1
// baseline (303.157 us; speedup 1.0000x reference)
//
#include <hip/hip_runtime.h>
#include <hip/hip_bf16.h>

#define BATCH 8
#define NN 2048
#define FIN 256
#define FOUT 128
#define ROWS (BATCH*NN)
#define NP1 (NN+1)
#define CHK 64           // chunks per batch
#define CLEN (NN/CHK)    // 32 rows per chunk
#define MIDBLKS 512

__device__ __forceinline__ unsigned pack2(float a, float b){
  __hip_bfloat16 x = __float2bfloat16(a), y = __float2bfloat16(b);
  unsigned short ux = *(unsigned short*)&x, uy = *(unsigned short*)&y;
  return ((unsigned)uy << 16) | (unsigned)ux;
}
__device__ __forceinline__ float lo2f(unsigned u){ union{unsigned v;float f;}c; c.v = u << 16; return c.f; }
__device__ __forceinline__ float hi2f(unsigned u){ union{unsigned v;float f;}c; c.v = u & 0xffff0000u; return c.f; }

// Monotonic-count global barrier. All 512 blocks (128 thr, ~100 VGPR, 1KB LDS)
// are trivially co-resident on 256 CUs (>=4x capacity margin at any plausible
// register count), so spin cannot deadlock. atomics are device-scope (m20);
// __threadfence() provides agent-scope release/acquire incl. L2 wb/inv (G16).
__device__ __forceinline__ void gbar(int* cnt, int target){
  __syncthreads();
  if (threadIdx.x == 0){
    __threadfence();
    atomicAdd(cnt, 1);
    while (__hip_atomic_load(cnt, __ATOMIC_ACQUIRE, __HIP_MEMORY_SCOPE_AGENT) < target)
      __builtin_amdgcn_s_sleep(2);
    __threadfence();
  }
  __syncthreads();
}

// ---------------- K1: tiled Wh = h @ W + fused s_i/s_j ----------------
// 32x128 block tile, 128 threads, 8x4 per-thread tile: 3 ds_read_b128 per
// 32 FMA (1.5 B/FMA vs previous 2.0) -> off the 256 B/clk LDS ceiling.
// Global staging register-double-buffered to cover latency at 4 waves/CU.
__global__ __launch_bounds__(128) void k_gemm(const float* __restrict__ h,
                                              const float* __restrict__ W,
                                              const float* __restrict__ ai,
                                              const float* __restrict__ aj,
                                              float* __restrict__ Wh,
                                              float* __restrict__ sI,
                                              float* __restrict__ sJ,
                                              int* __restrict__ bar){
  if (blockIdx.x == 0 && threadIdx.x == 0) *bar = 0;   // reset k_mid's barrier
  __shared__ float As[32][36];    // [k][m], pad 36 keeps 16B row alignment
  __shared__ float Bs[32][128];   // [k][o]
  const int t = threadIdx.x;
  const int rbase = blockIdx.x * 32;
  const int tx = t & 31, ty = t >> 5;      // ty 0..3
  const int o0 = tx * 4, m0 = ty * 8;
  float acc[8][4] = {};
  float4 hreg[2], wreg[8];

  // prologue: load tile 0 into regs
  #pragma unroll
  for (int u = 0; u < 2; u++){
    const int idx = t + u * 128;
    const int ar = idx >> 3, ak = (idx & 7) * 4;
    hreg[u] = *(const float4*)&h[(size_t)(rbase + ar) * FIN + ak];
  }
  #pragma unroll
  for (int u = 0; u < 8; u++){
    const int idx = t + u * 128;
    const int kk = idx >> 5, q = idx & 31;
    wreg[u] = *(const float4*)&W[(size_t)kk * FOUT + q * 4];
  }

  for (int k0 = 0; k0 < FIN; k0 += 32){
    // regs -> LDS
    #pragma unroll
    for (int u = 0; u < 2; u++){
      const int idx = t + u * 128;
      const int ar = idx >> 3, ak = (idx & 7) * 4;
      As[ak + 0][ar] = hreg[u].x; As[ak + 1][ar] = hreg[u].y;
      As[ak + 2][ar] = hreg[u].z; As[ak + 3][ar] = hreg[u].w;
    }
    #pragma unroll
    for (int u = 0; u < 8; u++){
      const int idx = t + u * 128;
      const int kk = idx >> 5, q = idx & 31;
      *(float4*)&Bs[kk][q * 4] = wreg[u];
    }
    __syncthreads();
    // prefetch next tile into regs while computing this one
    if (k0 + 32 < FIN){
      #pragma unroll
      for (int u = 0; u < 2; u++){
        const int idx = t + u * 128;
        const int ar = idx >> 3, ak = (idx & 7) * 4;
        hreg[u] = *(const float4*)&h[(size_t)(rbase + ar) * FIN + k0 + 32 + ak];
      }
      #pragma unroll
      for (int u = 0; u < 8; u++){
        const int idx = t + u * 128;
        const int kk = idx >> 5, q = idx & 31;
        wreg[u] = *(const float4*)&W[(size_t)(k0 + 32 + kk) * FOUT + q * 4];
      }
    }
    #pragma unroll
    for (int kk = 0; kk < 32; kk++){
      const float4 a0 = *(const float4*)&As[kk][m0];      // 2-addr broadcast
      const float4 a1 = *(const float4*)&As[kk][m0 + 4];
      const float4 bv = *(const float4*)&Bs[kk][o0];      // stride-1 b128
      const float am[8] = {a0.x, a0.y, a0.z, a0.w, a1.x, a1.y, a1.z, a1.w};
      #pragma unroll
      for (int i = 0; i < 8; i++){
        acc[i][0] = fmaf(am[i], bv.x, acc[i][0]);
        acc[i][1] = fmaf(am[i], bv.y, acc[i][1]);
        acc[i][2] = fmaf(am[i], bv.z, acc[i][2]);
        acc[i][3] = fmaf(am[i], bv.w, acc[i][3]);
      }
    }
    __syncthreads();
  }
  const float4 av  = *(const float4*)&ai[o0];
  const float4 bjv = *(const float4*)&aj[o0];
  #pragma unroll
  for (int i = 0; i < 8; i++){
    const int row = rbase + m0 + i;
    float4 vv = {acc[i][0], acc[i][1], acc[i][2], acc[i][3]};
    *(float4*)&Wh[(size_t)row * FOUT + o0] = vv;
    float pi = vv.x * av.x + vv.y * av.y + vv.z * av.z + vv.w * av.w;
    float pj = vv.x * bjv.x + vv.y * bjv.y + vv.z * bjv.z + vv.w * bjv.w;
    #pragma unroll
    for (int m = 1; m < 32; m <<= 1){   // xor masks <32 stay in the tx-group
      pi += __shfl_xor(pi, m);
      pj += __shfl_xor(pj, m);
    }
    if (tx == 0){ sI[row] = pi; sJ[row] = pj; }
  }
}

// ---------------- K_mid: rankp -> scatter -> chunk totals -> scans+P12 ----
// One kernel, 512 blocks x 128 threads, 3 global barriers. Gathered Wh rows
// stay in VGPRs from phase B to phase C (removes the second 8 MB gather).
__global__ __launch_bounds__(128) void k_mid(const float* __restrict__ sJ,
                                             const float* __restrict__ Wh,
                                             int* __restrict__ rankPart,
                                             float* __restrict__ sortedS,
                                             int* __restrict__ perm,
                                             float* __restrict__ e1g,
                                             float* __restrict__ e2g,
                                             float* __restrict__ E1g,
                                             float* __restrict__ E2g,
                                             float* __restrict__ T1,
                                             float* __restrict__ T2,
                                             float* __restrict__ aPre,
                                             float* __restrict__ bPre,
                                             unsigned* __restrict__ P12,
                                             int* __restrict__ bar){
  __shared__ float v[256];
  const int t = threadIdx.x;
  const int blk = blockIdx.x;

  // ---- P0: partial rank counts (was k_rankp; 2 j's per thread) ----
  {
    const int b = blk >> 6, jc = (blk >> 3) & 7, qc = blk & 7;
    const int qbase = qc * 256;
    const float* sj = sJ + b * NN;
    v[t]       = sj[qbase + t];
    v[t + 128] = sj[qbase + t + 128];
    const int j0 = jc * 256 + t, j1 = j0 + 128;
    const float x0 = sj[j0], x1 = sj[j1];
    __syncthreads();
    int r0 = 0, r1 = 0;
    #pragma unroll 4
    for (int q4 = 0; q4 < 64; q4++){
      const int q = q4 * 4;
      float4 y = *(const float4*)&v[q];
      r0 += (y.x < x0) || (y.x == x0 && (qbase + q + 0) < j0);
      r0 += (y.y < x0) || (y.y == x0 && (qbase + q + 1) < j0);
      r0 += (y.z < x0) || (y.z == x0 && (qbase + q + 2) < j0);
      r0 += (y.w < x0) || (y.w == x0 && (qbase + q + 3) < j0);
      r1 += (y.x < x1) || (y.x == x1 && (qbase + q + 0) < j1);
      r1 += (y.y < x1) || (y.y == x1 && (qbase + q + 1) < j1);
      r1 += (y.z < x1) || (y.z == x1 && (qbase + q + 2) < j1);
      r1 += (y.w < x1) || (y.w == x1 && (qbase + q + 3) < j1);
    }
    int* rp = rankPart + (size_t)(b * 8 + qc) * NN;
    rp[j0] = r0;
    rp[j1] = r1;
  }
  gbar(bar, MIDBLKS);

  // ---- A: combine ranks, scatter sorted arrays (was k_scatter) ----
  if (blk < 128){
    const int gid = blk * 128 + t;            // 0..16383
    const int b = gid >> 11, j = gid & (NN - 1);
    int r = 0;
    #pragma unroll
    for (int qc = 0; qc < 8; qc++) r += rankPart[(size_t)(b * 8 + qc) * NN + j];
    const float x = sJ[b * NN + j];
    sortedS[b * NN + r] = x;
    perm[b * NN + r] = j;
    e1g[b * NN + r] = expf(x);
    e2g[b * NN + r] = expf(0.01f * x);
  }
  gbar(bar, 2 * MIDBLKS);

  // ---- B: per-chunk vector + scalar totals; keep gathered w in regs ----
  const int b = blk >> 6, c = blk & 63;
  const int g0 = c * CLEN;
  const int o = t;                            // 0..127
  const float* whb = Wh + (size_t)b * NN * FOUT;
  const int*   pm  = perm + b * NN + g0;
  const float* e1p = e1g + b * NN + g0;
  const float* e2p = e2g + b * NN + g0;
  float w[CLEN];
  float t1 = 0.f, t2 = 0.f, s1 = 0.f, s2 = 0.f;
  #pragma unroll
  for (int r = 0; r < CLEN; r++){             // full unroll: static w[] indices
    w[r] = whb[(size_t)pm[r] * FOUT + o];
    const float u1 = e1p[r], u2 = e2p[r];
    t1 = fmaf(u1, w[r], t1);
    t2 = fmaf(u2, w[r], t2);
    s1 += u1; s2 += u2;
  }
  T1[(size_t)(b * CHK + c) * FOUT + o] = t1;
  T2[(size_t)(b * CHK + c) * FOUT + o] = t2;
  if (t == 0){ E1g[b * CHK + c] = s1; E2g[b * CHK + c] = s2; }
  gbar(bar, 3 * MIDBLKS);

  // ---- C: offsets + scalar scans (was k_sscan) + P12 (was k_scan2) ----
  float offA, offB;
  {
    const int l = t & 63;
    float a = (l < c) ? E1g[b * CHK + l] : 0.f;
    float e = (l < c) ? E2g[b * CHK + l] : 0.f;
    #pragma unroll
    for (int m = 1; m < 64; m <<= 1){ a += __shfl_xor(a, m); e += __shfl_xor(e, m); }
    offA = a; offB = e;
  }
  if (t < 32){
    float v1 = e1p[t], v2 = e2p[t];
    #pragma unroll
    for (int d = 1; d < 32; d <<= 1){
      const float u1 = __shfl_up(v1, d, 32);
      const float u2 = __shfl_up(v2, d, 32);
      if (t >= d){ v1 += u1; v2 += u2; }
    }
    aPre[b * NP1 + g0 + t + 1] = offA + v1;
    bPre[b * NP1 + g0 + t + 1] = offB + v2;
    if (c == 0 && t == 0){ aPre[b * NP1] = 0.f; bPre[b * NP1] = 0.f; }
  }
  float acc1 = 0.f, acc2 = 0.f;
  for (int q = 0; q < c; q++){
    acc1 += T1[(size_t)(b * CHK + q) * FOUT + o];
    acc2 += T2[(size_t)(b * CHK + q) * FOUT + o];
  }
  unsigned* p = P12 + (size_t)b * NP1 * FOUT + o;
  if (c == 0) p[0] = 0u;
  #pragma unroll
  for (int r = 0; r < CLEN; r++){
    acc1 = fmaf(e1p[r], w[r], acc1);
    acc2 = fmaf(e2p[r], w[r], acc2);
    p[(size_t)(g0 + r + 1) * FOUT] = pack2(acc1, acc2);
  }
}

// ---------------- K5: per-row combine, fp32 store (packed P reads) ----------------
__global__ __launch_bounds__(128) void k_out(const float* __restrict__ sI,
                                             const float* __restrict__ sortedS,
                                             const float* __restrict__ aPre,
                                             const float* __restrict__ bPre,
                                             const unsigned* __restrict__ P12,
                                             float* __restrict__ out){
  const int row = blockIdx.x;
  const int b = row >> 11;
  const float s = sI[row];
  const float key = -s;
  const float* ss = sortedS + b * NN;
  int lo = 0, hi = NN;
  while (lo < hi){
    int mid = (lo + hi) >> 1;
    if (ss[mid] <= key) lo = mid + 1; else hi = mid;
  }
  const int k = lo;
  const float w1 = expf(s), w2 = expf(0.01f * s);
  const float aT = aPre[b * NP1 + NN];
  const float ak = aPre[b * NP1 + k];
  const float bk = bPre[b * NP1 + k];
  const float inv = 1.0f / (w1 * (aT - ak) + w2 * bk);
  const int o = threadIdx.x;
  const unsigned uk = P12[((size_t)b * NP1 + k) * FOUT + o];
  const unsigned uT = P12[((size_t)b * NP1 + NN) * FOUT + o];
  float num = w1 * (lo2f(uT) - lo2f(uk)) + w2 * hi2f(uk);
  out[(size_t)row * FOUT + o] = num * inv;
}

extern "C" void kernel_launch(void* const* d_in, const int* in_sizes, int n_in,
                              void* d_out, int out_size, void* d_ws, size_t ws_size,
                              hipStream_t stream){
  const float* h  = (const float*)d_in[0];
  const float* W  = (const float*)d_in[1];
  const float* ai = (const float*)d_in[2];
  const float* aj = (const float*)d_in[3];
  float* out = (float*)d_out;

  char* ws = (char*)d_ws;
  size_t off = 0;
  auto alloc = [&](size_t bytes) -> void* {
    void* p = ws + off;
    off += (bytes + 255) & ~(size_t)255;
    return p;
  };
  float*    Wh       = (float*)   alloc((size_t)ROWS * FOUT * 4);        // 8 MB
  float*    sI       = (float*)   alloc((size_t)ROWS * 4);
  float*    sJ       = (float*)   alloc((size_t)ROWS * 4);
  float*    sortedS  = (float*)   alloc((size_t)BATCH * NN * 4);
  int*      perm     = (int*)     alloc((size_t)BATCH * NN * 4);
  float*    e1       = (float*)   alloc((size_t)BATCH * NN * 4);
  float*    e2       = (float*)   alloc((size_t)BATCH * NN * 4);
  float*    aPre     = (float*)   alloc((size_t)BATCH * NP1 * 4);
  float*    bPre     = (float*)   alloc((size_t)BATCH * NP1 * 4);
  int*      rankPart = (int*)     alloc((size_t)BATCH * 8 * NN * 4);     // 512 KB
  float*    T1       = (float*)   alloc((size_t)BATCH * CHK * FOUT * 4); // 256 KB
  float*    T2       = (float*)   alloc((size_t)BATCH * CHK * FOUT * 4); // 256 KB
  unsigned* P12      = (unsigned*)alloc((size_t)BATCH * NP1 * FOUT * 4); // 8.4 MB
  float*    E1g      = (float*)   alloc((size_t)BATCH * CHK * 4);
  float*    E2g      = (float*)   alloc((size_t)BATCH * CHK * 4);
  int*      bar      = (int*)     alloc(256);

  k_gemm<<<ROWS / 32, 128, 0, stream>>>(h, W, ai, aj, Wh, sI, sJ, bar);
  k_mid <<<MIDBLKS, 128, 0, stream>>>(sJ, Wh, rankPart, sortedS, perm, e1, e2,
                                      E1g, E2g, T1, T2, aPre, bPre, P12, bar);
  k_out <<<ROWS, 128, 0, stream>>>(sI, sortedS, aPre, bPre, P12, out);
}

// Round 2
// 135.569 us; speedup vs baseline: 2.2362x; 2.2362x over previous
//
#include <hip/hip_runtime.h>
#include <hip/hip_bf16.h>

#define BATCH 8
#define NN 2048
#define FIN 256
#define FOUT 128
#define ROWS (BATCH*NN)
#define NP1 (NN+1)
#define CHK 128          // chunks per batch (was 64): 2048 waves = 2/SIMD in scan pair
#define CLEN (NN/CHK)    // 16 rows per chunk

__device__ __forceinline__ unsigned pack2(float a, float b){
  __hip_bfloat16 x = __float2bfloat16(a), y = __float2bfloat16(b);
  unsigned short ux = *(unsigned short*)&x, uy = *(unsigned short*)&y;
  return ((unsigned)uy << 16) | (unsigned)ux;
}
__device__ __forceinline__ float lo2f(unsigned u){ union{unsigned v;float f;}c; c.v = u << 16; return c.f; }
__device__ __forceinline__ float hi2f(unsigned u){ union{unsigned v;float f;}c; c.v = u & 0xffff0000u; return c.f; }

// ---------------- K1: tiled Wh = h @ W + fused s_i/s_j (r0-proven) ----------------
__global__ __launch_bounds__(256) void k_gemm(const float* __restrict__ h,
                                              const float* __restrict__ W,
                                              const float* __restrict__ ai,
                                              const float* __restrict__ aj,
                                              float* __restrict__ Wh,
                                              float* __restrict__ sI,
                                              float* __restrict__ sJ){
  __shared__ float As[32][36];    // [k][m], pad 36 (16B-aligned rows)
  __shared__ float Bs[32][128];   // [k][o]
  const int t = threadIdx.x;
  const int rbase = blockIdx.x * 32;
  const int tx = t & 31, ty = t >> 5;
  const int o0 = tx * 4, m0 = ty * 4;
  const int ar = t >> 3, ak = (t & 7) * 4;
  float acc[4][4] = {};
  for (int k0 = 0; k0 < FIN; k0 += 32){
    {
      float4 hv = *(const float4*)&h[(size_t)(rbase + ar) * FIN + k0 + ak];
      As[ak + 0][ar] = hv.x; As[ak + 1][ar] = hv.y;
      As[ak + 2][ar] = hv.z; As[ak + 3][ar] = hv.w;
    }
    #pragma unroll
    for (int u = 0; u < 4; u++){
      int idx = t + u * 256;
      int kk = idx >> 5, q = idx & 31;
      *(float4*)&Bs[kk][q * 4] = *(const float4*)&W[(size_t)(k0 + kk) * FOUT + q * 4];
    }
    __syncthreads();
    #pragma unroll
    for (int kk = 0; kk < 32; kk++){
      float4 a4 = *(const float4*)&As[kk][m0];   // broadcast b128
      float4 bv = *(const float4*)&Bs[kk][o0];   // stride-1 b128
      acc[0][0] = fmaf(a4.x, bv.x, acc[0][0]); acc[0][1] = fmaf(a4.x, bv.y, acc[0][1]);
      acc[0][2] = fmaf(a4.x, bv.z, acc[0][2]); acc[0][3] = fmaf(a4.x, bv.w, acc[0][3]);
      acc[1][0] = fmaf(a4.y, bv.x, acc[1][0]); acc[1][1] = fmaf(a4.y, bv.y, acc[1][1]);
      acc[1][2] = fmaf(a4.y, bv.z, acc[1][2]); acc[1][3] = fmaf(a4.y, bv.w, acc[1][3]);
      acc[2][0] = fmaf(a4.z, bv.x, acc[2][0]); acc[2][1] = fmaf(a4.z, bv.y, acc[2][1]);
      acc[2][2] = fmaf(a4.z, bv.z, acc[2][2]); acc[2][3] = fmaf(a4.z, bv.w, acc[2][3]);
      acc[3][0] = fmaf(a4.w, bv.x, acc[3][0]); acc[3][1] = fmaf(a4.w, bv.y, acc[3][1]);
      acc[3][2] = fmaf(a4.w, bv.z, acc[3][2]); acc[3][3] = fmaf(a4.w, bv.w, acc[3][3]);
    }
    __syncthreads();
  }
  const float4 av = *(const float4*)&ai[o0];
  const float4 bjv = *(const float4*)&aj[o0];
  #pragma unroll
  for (int i = 0; i < 4; i++){
    float4 v = {acc[i][0], acc[i][1], acc[i][2], acc[i][3]};
    *(float4*)&Wh[(size_t)(rbase + m0 + i) * FOUT + o0] = v;
    float pi = v.x * av.x + v.y * av.y + v.z * av.z + v.w * av.w;
    float pj = v.x * bjv.x + v.y * bjv.y + v.z * bjv.z + v.w * bjv.w;
    #pragma unroll
    for (int m = 1; m < 32; m <<= 1){
      pi += __shfl_xor(pi, m);
      pj += __shfl_xor(pj, m);
    }
    if (tx == 0){
      sI[rbase + m0 + i] = pi;
      sJ[rbase + m0 + i] = pj;
    }
  }
}

// ---------------- K2a: partial rank counts (r0-proven) ----------------
__global__ __launch_bounds__(256) void k_rankp(const float* __restrict__ sJ,
                                               int* __restrict__ rankPart){
  const int blk = blockIdx.x;
  const int jc = blk & 7;
  const int qc = (blk >> 3) & 7;
  const int b  = blk >> 6;
  __shared__ float v[256];
  const int t = threadIdx.x;
  const int qbase = qc * 256;
  v[t] = sJ[b * NN + qbase + t];
  const int j = jc * 256 + t;
  const float x = sJ[b * NN + j];
  __syncthreads();
  int r = 0;
  #pragma unroll 4
  for (int q4 = 0; q4 < 64; q4++){
    const int q = q4 * 4;
    float4 y = *(const float4*)&v[q];
    r += (y.x < x) || (y.x == x && (qbase + q + 0) < j);
    r += (y.y < x) || (y.y == x && (qbase + q + 1) < j);
    r += (y.z < x) || (y.z == x && (qbase + q + 2) < j);
    r += (y.w < x) || (y.w == x && (qbase + q + 3) < j);
  }
  rankPart[((size_t)(b * 8 + qc)) * NN + j] = r;
}

// ---------------- K2b: combine partials, scatter sorted arrays (r0-proven) ----------------
__global__ __launch_bounds__(256) void k_scatter(const float* __restrict__ sJ,
                                                 const int* __restrict__ rankPart,
                                                 float* __restrict__ sortedS,
                                                 int* __restrict__ perm,
                                                 float* __restrict__ e1g,
                                                 float* __restrict__ e2g){
  const int b = blockIdx.x >> 3;
  const int jc = blockIdx.x & 7;
  const int j = jc * 256 + threadIdx.x;
  int r = 0;
  #pragma unroll
  for (int qc = 0; qc < 8; qc++)
    r += rankPart[((size_t)(b * 8 + qc)) * NN + j];
  const float x = sJ[b * NN + j];
  sortedS[b * NN + r] = x;
  perm[b * NN + r] = j;
  e1g[b * NN + r] = expf(x);
  e2g[b * NN + r] = expf(0.01f * x);
}

// ---------------- K3∪K4a merged: blocks 0-7 scalar scans; blocks 8+ chunk totals ----
// Both depend only on scatter output, independent of each other -> one dispatch.
__global__ __launch_bounds__(256) void k_sscan_csum(const float* __restrict__ e1g,
                                                    const float* __restrict__ e2g,
                                                    const float* __restrict__ Wh,
                                                    const int* __restrict__ perm,
                                                    float* __restrict__ aPre,
                                                    float* __restrict__ bPre,
                                                    float* __restrict__ T1,
                                                    float* __restrict__ T2){
  const int t = threadIdx.x;
  if (blockIdx.x < BATCH){
    // ---- scalar inclusive prefix sums of e1, e2 (r0 k_sscan body) ----
    const int b = blockIdx.x;
    __shared__ float p1[256], p2[256];
    __shared__ float x1[256], x2[256];
    const float* e1 = e1g + b * NN;
    const float* e2 = e2g + b * NN;
    float l1[8], l2[8];
    float s1 = 0.f, s2 = 0.f;
    #pragma unroll
    for (int q = 0; q < 8; q++){
      s1 += e1[t * 8 + q]; l1[q] = s1;
      s2 += e2[t * 8 + q]; l2[q] = s2;
    }
    p1[t] = s1; p2[t] = s2;
    __syncthreads();
    if (t == 0){
      float a = 0.f, c = 0.f;
      for (int q = 0; q < 256; q++){
        x1[q] = a; a += p1[q];
        x2[q] = c; c += p2[q];
      }
    }
    __syncthreads();
    const float b1 = x1[t], b2 = x2[t];
    float* aP = aPre + b * NP1;
    float* bP = bPre + b * NP1;
    #pragma unroll
    for (int q = 0; q < 8; q++){
      aP[1 + t * 8 + q] = b1 + l1[q];
      bP[1 + t * 8 + q] = b2 + l2[q];
    }
    if (t == 0){ aP[0] = 0.f; bP[0] = 0.f; }
  } else {
    // ---- per-chunk vector totals; 2 chunks per 256-thr block ----
    const int bc = blockIdx.x - BATCH;          // 0..511
    const int b = bc >> 6, cp = bc & 63;
    const int c = cp * 2 + (t >> 7);            // 0..127
    const int o = t & 127;
    const int g0 = c * CLEN;
    const int* pm = perm + b * NN + g0;
    const float* e1 = e1g + b * NN + g0;
    const float* e2 = e2g + b * NN + g0;
    const float* whb = Wh + (size_t)b * NN * FOUT;
    float t1 = 0.f, t2 = 0.f;
    #pragma unroll
    for (int r = 0; r < CLEN; r++){
      float w = whb[(size_t)pm[r] * FOUT + o];
      t1 = fmaf(e1[r], w, t1);
      t2 = fmaf(e2[r], w, t2);
    }
    T1[(size_t)(b * CHK + c) * FOUT + o] = t1;
    T2[(size_t)(b * CHK + c) * FOUT + o] = t2;
  }
}

// ---------------- K4b: chunk-offset + local scan -> PACKED bf16x2 P ----------------
__global__ __launch_bounds__(128) void k_scan2(const float* __restrict__ Wh,
                                               const int* __restrict__ perm,
                                               const float* __restrict__ e1g,
                                               const float* __restrict__ e2g,
                                               const float* __restrict__ T1,
                                               const float* __restrict__ T2,
                                               unsigned* __restrict__ P12){
  const int b = blockIdx.x >> 7;                // CHK=128
  const int c = blockIdx.x & 127;
  const int o = threadIdx.x;
  float acc1 = 0.f, acc2 = 0.f;
  #pragma unroll 4
  for (int q = 0; q < c; q++){
    acc1 += T1[(size_t)(b * CHK + q) * FOUT + o];
    acc2 += T2[(size_t)(b * CHK + q) * FOUT + o];
  }
  const int g0 = c * CLEN;
  const int* pm = perm + b * NN + g0;
  const float* e1 = e1g + b * NN + g0;
  const float* e2 = e2g + b * NN + g0;
  const float* whb = Wh + (size_t)b * NN * FOUT;
  unsigned* p = P12 + (size_t)b * NP1 * FOUT + o;
  if (c == 0) p[0] = 0u;
  #pragma unroll
  for (int r = 0; r < CLEN; r++){
    float w = whb[(size_t)pm[r] * FOUT + o];
    acc1 = fmaf(e1[r], w, acc1);
    acc2 = fmaf(e2[r], w, acc2);
    p[(size_t)(g0 + r + 1) * FOUT] = pack2(acc1, acc2);
  }
}

// ---------------- K5: per-row combine, fp32 store (r0-proven) ----------------
__global__ __launch_bounds__(128) void k_out(const float* __restrict__ sI,
                                             const float* __restrict__ sortedS,
                                             const float* __restrict__ aPre,
                                             const float* __restrict__ bPre,
                                             const unsigned* __restrict__ P12,
                                             float* __restrict__ out){
  const int row = blockIdx.x;
  const int b = row >> 11;
  const float s = sI[row];
  const float key = -s;
  const float* ss = sortedS + b * NN;
  int lo = 0, hi = NN;
  while (lo < hi){
    int mid = (lo + hi) >> 1;
    if (ss[mid] <= key) lo = mid + 1; else hi = mid;
  }
  const int k = lo;
  const float w1 = expf(s), w2 = expf(0.01f * s);
  const float aT = aPre[b * NP1 + NN];
  const float ak = aPre[b * NP1 + k];
  const float bk = bPre[b * NP1 + k];
  const float inv = 1.0f / (w1 * (aT - ak) + w2 * bk);
  const int o = threadIdx.x;
  const unsigned uk = P12[((size_t)b * NP1 + k) * FOUT + o];
  const unsigned uT = P12[((size_t)b * NP1 + NN) * FOUT + o];
  float num = w1 * (lo2f(uT) - lo2f(uk)) + w2 * hi2f(uk);
  out[(size_t)row * FOUT + o] = num * inv;
}

extern "C" void kernel_launch(void* const* d_in, const int* in_sizes, int n_in,
                              void* d_out, int out_size, void* d_ws, size_t ws_size,
                              hipStream_t stream){
  const float* h  = (const float*)d_in[0];
  const float* W  = (const float*)d_in[1];
  const float* ai = (const float*)d_in[2];
  const float* aj = (const float*)d_in[3];
  float* out = (float*)d_out;

  char* ws = (char*)d_ws;
  size_t off = 0;
  auto alloc = [&](size_t bytes) -> void* {
    void* p = ws + off;
    off += (bytes + 255) & ~(size_t)255;
    return p;
  };
  float*    Wh       = (float*)   alloc((size_t)ROWS * FOUT * 4);        // 8 MB
  float*    sI       = (float*)   alloc((size_t)ROWS * 4);
  float*    sJ       = (float*)   alloc((size_t)ROWS * 4);
  float*    sortedS  = (float*)   alloc((size_t)BATCH * NN * 4);
  int*      perm     = (int*)     alloc((size_t)BATCH * NN * 4);
  float*    e1       = (float*)   alloc((size_t)BATCH * NN * 4);
  float*    e2       = (float*)   alloc((size_t)BATCH * NN * 4);
  float*    aPre     = (float*)   alloc((size_t)BATCH * NP1 * 4);
  float*    bPre     = (float*)   alloc((size_t)BATCH * NP1 * 4);
  int*      rankPart = (int*)     alloc((size_t)BATCH * 8 * NN * 4);     // 512 KB
  float*    T1       = (float*)   alloc((size_t)BATCH * CHK * FOUT * 4); // 512 KB
  float*    T2       = (float*)   alloc((size_t)BATCH * CHK * FOUT * 4); // 512 KB
  unsigned* P12      = (unsigned*)alloc((size_t)BATCH * NP1 * FOUT * 4); // 8.4 MB

  k_gemm      <<<ROWS / 32, 256, 0, stream>>>(h, W, ai, aj, Wh, sI, sJ);
  k_rankp     <<<BATCH * 64, 256, 0, stream>>>(sJ, rankPart);
  k_scatter   <<<BATCH * 8, 256, 0, stream>>>(sJ, rankPart, sortedS, perm, e1, e2);
  k_sscan_csum<<<BATCH + BATCH * CHK / 2, 256, 0, stream>>>(e1, e2, Wh, perm, aPre, bPre, T1, T2);
  k_scan2     <<<BATCH * CHK, 128, 0, stream>>>(Wh, perm, e1, e2, T1, T2, P12);
  k_out       <<<ROWS, 128, 0, stream>>>(sI, sortedS, aPre, bPre, P12, out);
}

// Round 3
// 135.321 us; speedup vs baseline: 2.2403x; 1.0018x over previous
//
#include <hip/hip_runtime.h>
#include <hip/hip_bf16.h>

#define BATCH 8
#define NN 2048
#define FIN 256
#define FOUT 128
#define ROWS (BATCH*NN)
#define NP1 (NN+1)
#define SEGS 64          // row segments per batch in k_fuse
#define SLEN (NN/SEGS)   // 32 rows per segment

__device__ __forceinline__ unsigned pack2(float a, float b){
  __hip_bfloat16 x = __float2bfloat16(a), y = __float2bfloat16(b);
  unsigned short ux = *(unsigned short*)&x, uy = *(unsigned short*)&y;
  return ((unsigned)uy << 16) | (unsigned)ux;
}
__device__ __forceinline__ float lo2f(unsigned u){ union{unsigned v;float f;}c; c.v = u << 16; return c.f; }
__device__ __forceinline__ float hi2f(unsigned u){ union{unsigned v;float f;}c; c.v = u & 0xffff0000u; return c.f; }

// ---------------- K1: tiled Wh = h @ W + fused s_i/s_j (r0/r2-proven) ----------------
__global__ __launch_bounds__(256) void k_gemm(const float* __restrict__ h,
                                              const float* __restrict__ W,
                                              const float* __restrict__ ai,
                                              const float* __restrict__ aj,
                                              float* __restrict__ Wh,
                                              float* __restrict__ sI,
                                              float* __restrict__ sJ){
  __shared__ float As[32][36];    // [k][m], pad 36 (16B-aligned rows)
  __shared__ float Bs[32][128];   // [k][o]
  const int t = threadIdx.x;
  const int rbase = blockIdx.x * 32;
  const int tx = t & 31, ty = t >> 5;
  const int o0 = tx * 4, m0 = ty * 4;
  const int ar = t >> 3, ak = (t & 7) * 4;
  float acc[4][4] = {};
  for (int k0 = 0; k0 < FIN; k0 += 32){
    {
      float4 hv = *(const float4*)&h[(size_t)(rbase + ar) * FIN + k0 + ak];
      As[ak + 0][ar] = hv.x; As[ak + 1][ar] = hv.y;
      As[ak + 2][ar] = hv.z; As[ak + 3][ar] = hv.w;
    }
    #pragma unroll
    for (int u = 0; u < 4; u++){
      int idx = t + u * 256;
      int kk = idx >> 5, q = idx & 31;
      *(float4*)&Bs[kk][q * 4] = *(const float4*)&W[(size_t)(k0 + kk) * FOUT + q * 4];
    }
    __syncthreads();
    #pragma unroll
    for (int kk = 0; kk < 32; kk++){
      float4 a4 = *(const float4*)&As[kk][m0];   // broadcast b128
      float4 bv = *(const float4*)&Bs[kk][o0];   // stride-1 b128
      acc[0][0] = fmaf(a4.x, bv.x, acc[0][0]); acc[0][1] = fmaf(a4.x, bv.y, acc[0][1]);
      acc[0][2] = fmaf(a4.x, bv.z, acc[0][2]); acc[0][3] = fmaf(a4.x, bv.w, acc[0][3]);
      acc[1][0] = fmaf(a4.y, bv.x, acc[1][0]); acc[1][1] = fmaf(a4.y, bv.y, acc[1][1]);
      acc[1][2] = fmaf(a4.y, bv.z, acc[1][2]); acc[1][3] = fmaf(a4.y, bv.w, acc[1][3]);
      acc[2][0] = fmaf(a4.z, bv.x, acc[2][0]); acc[2][1] = fmaf(a4.z, bv.y, acc[2][1]);
      acc[2][2] = fmaf(a4.z, bv.z, acc[2][2]); acc[2][3] = fmaf(a4.z, bv.w, acc[2][3]);
      acc[3][0] = fmaf(a4.w, bv.x, acc[3][0]); acc[3][1] = fmaf(a4.w, bv.y, acc[3][1]);
      acc[3][2] = fmaf(a4.w, bv.z, acc[3][2]); acc[3][3] = fmaf(a4.w, bv.w, acc[3][3]);
    }
    __syncthreads();
  }
  const float4 av = *(const float4*)&ai[o0];
  const float4 bjv = *(const float4*)&aj[o0];
  #pragma unroll
  for (int i = 0; i < 4; i++){
    float4 v = {acc[i][0], acc[i][1], acc[i][2], acc[i][3]};
    *(float4*)&Wh[(size_t)(rbase + m0 + i) * FOUT + o0] = v;
    float pi = v.x * av.x + v.y * av.y + v.z * av.z + v.w * av.w;
    float pj = v.x * bjv.x + v.y * bjv.y + v.z * bjv.z + v.w * bjv.w;
    #pragma unroll
    for (int m = 1; m < 32; m <<= 1){
      pi += __shfl_xor(pi, m);
      pj += __shfl_xor(pj, m);
    }
    if (tx == 0){
      sI[rbase + m0 + i] = pi;
      sJ[rbase + m0 + i] = pj;
    }
  }
}

// ---------------- K2: one-shot rank + scatter (merged k_rankp + k_scatter) ----------
// Block = (b, 64 j's). Full sJ[b] cached in LDS (8 KB); thread (jj,qq) compares
// j against a 512-wide q-quarter; LDS-reduce 4 partials -> exact rank -> scatter.
__global__ __launch_bounds__(256) void k_rank_scatter(const float* __restrict__ sJ,
                                                      float* __restrict__ sortedS,
                                                      int* __restrict__ perm,
                                                      float* __restrict__ e1g,
                                                      float* __restrict__ e2g){
  const int b = blockIdx.x >> 5;        // 32 blocks per batch
  const int jc = blockIdx.x & 31;       // 64 j's per block
  __shared__ float v[NN];               // 8 KB
  __shared__ int partial[4][64];
  const int t = threadIdx.x;
  const float* sj = sJ + b * NN;
  for (int u = t; u < NN; u += 256) v[u] = sj[u];
  const int jj = t & 63, qq = t >> 6;
  const int j = jc * 64 + jj;
  const float x = sj[j];
  __syncthreads();
  const int q0 = qq * 512;
  int r = 0;
  #pragma unroll 8
  for (int q4 = 0; q4 < 128; q4++){
    const int q = q0 + q4 * 4;
    float4 y = *(const float4*)&v[q];
    r += (y.x < x) || (y.x == x && (q + 0) < j);
    r += (y.y < x) || (y.y == x && (q + 1) < j);
    r += (y.z < x) || (y.z == x && (q + 2) < j);
    r += (y.w < x) || (y.w == x && (q + 3) < j);
  }
  partial[qq][jj] = r;
  __syncthreads();
  if (t < 64){
    const int R = partial[0][t] + partial[1][t] + partial[2][t] + partial[3][t];
    const int myj = jc * 64 + t;
    const float xx = v[myj];
    sortedS[b * NN + R] = xx;
    perm[b * NN + R] = myj;
    e1g[b * NN + R] = expf(xx);
    e2g[b * NN + R] = expf(0.01f * xx);
  }
}

// ---------------- K3: fused scans (merged k_sscan + k_csum + k_scan2) -------------
// Blocks 0-7: scalar e-prefix sums -> aPre/bPre (verbatim r2).
// Blocks 8-263: (b, 4-output-cols). Thread (ol,seg): gather 32 Wh values ONCE
// into regs, per-seg totals -> LDS Hillis-Steele prefix over 64 segs -> write
// P12 from the kept registers. No T1/T2, no second Wh gather.
__global__ __launch_bounds__(256) void k_fuse(const float* __restrict__ e1g,
                                              const float* __restrict__ e2g,
                                              const float* __restrict__ Wh,
                                              const int* __restrict__ perm,
                                              float* __restrict__ aPre,
                                              float* __restrict__ bPre,
                                              unsigned* __restrict__ P12){
  const int t = threadIdx.x;
  if (blockIdx.x < BATCH){
    const int b = blockIdx.x;
    __shared__ float p1[256], p2[256];
    __shared__ float x1[256], x2[256];
    const float* e1 = e1g + b * NN;
    const float* e2 = e2g + b * NN;
    float l1[8], l2[8];
    float s1 = 0.f, s2 = 0.f;
    #pragma unroll
    for (int q = 0; q < 8; q++){
      s1 += e1[t * 8 + q]; l1[q] = s1;
      s2 += e2[t * 8 + q]; l2[q] = s2;
    }
    p1[t] = s1; p2[t] = s2;
    __syncthreads();
    if (t == 0){
      float a = 0.f, c = 0.f;
      for (int q = 0; q < 256; q++){
        x1[q] = a; a += p1[q];
        x2[q] = c; c += p2[q];
      }
    }
    __syncthreads();
    const float b1 = x1[t], b2 = x2[t];
    float* aP = aPre + b * NP1;
    float* bP = bPre + b * NP1;
    #pragma unroll
    for (int q = 0; q < 8; q++){
      aP[1 + t * 8 + q] = b1 + l1[q];
      bP[1 + t * 8 + q] = b2 + l2[q];
    }
    if (t == 0){ aP[0] = 0.f; bP[0] = 0.f; }
    return;
  }
  // ---- fused column scan ----
  const int bc = blockIdx.x - BATCH;    // 0..255
  const int b = bc >> 5;                // 32 blocks per batch
  const int og = bc & 31;               // 4 output cols each
  const int ol = t & 3;
  const int o = og * 4 + ol;
  const int seg = t >> 2;               // 0..63
  const int r0 = seg * SLEN;
  __shared__ float p1[SEGS][4], p2[SEGS][4];
  const int*   pm  = perm + b * NN;
  const float* e1  = e1g  + b * NN;
  const float* e2  = e2g  + b * NN;
  const float* whb = Wh + (size_t)b * NN * FOUT;
  float w[SLEN];
  float t1 = 0.f, t2 = 0.f;
  #pragma unroll
  for (int r = 0; r < SLEN; r++){       // full unroll: static w[] indices
    w[r] = whb[(size_t)pm[r0 + r] * FOUT + o];
    const float u1 = e1[r0 + r], u2 = e2[r0 + r];
    t1 = fmaf(u1, w[r], t1);
    t2 = fmaf(u2, w[r], t2);
  }
  p1[seg][ol] = t1; p2[seg][ol] = t2;
  __syncthreads();
  #pragma unroll
  for (int d = 1; d < SEGS; d <<= 1){   // inclusive Hillis-Steele over segs
    const float u1 = (seg >= d) ? p1[seg - d][ol] : 0.f;
    const float u2 = (seg >= d) ? p2[seg - d][ol] : 0.f;
    __syncthreads();
    if (seg >= d){ p1[seg][ol] += u1; p2[seg][ol] += u2; }
    __syncthreads();
  }
  float acc1 = p1[seg][ol] - t1;        // exclusive offset
  float acc2 = p2[seg][ol] - t2;
  unsigned* pp = P12 + (size_t)b * NP1 * FOUT + o;
  if (seg == 0) pp[0] = 0u;
  #pragma unroll
  for (int r = 0; r < SLEN; r++){
    acc1 = fmaf(e1[r0 + r], w[r], acc1);
    acc2 = fmaf(e2[r0 + r], w[r], acc2);
    pp[(size_t)(r0 + r + 1) * FOUT] = pack2(acc1, acc2);
  }
}

// ---------------- K4: per-row combine, fp32 store (r0/r2-proven) ----------------
__global__ __launch_bounds__(128) void k_out(const float* __restrict__ sI,
                                             const float* __restrict__ sortedS,
                                             const float* __restrict__ aPre,
                                             const float* __restrict__ bPre,
                                             const unsigned* __restrict__ P12,
                                             float* __restrict__ out){
  const int row = blockIdx.x;
  const int b = row >> 11;
  const float s = sI[row];
  const float key = -s;
  const float* ss = sortedS + b * NN;
  int lo = 0, hi = NN;
  while (lo < hi){
    int mid = (lo + hi) >> 1;
    if (ss[mid] <= key) lo = mid + 1; else hi = mid;
  }
  const int k = lo;
  const float w1 = expf(s), w2 = expf(0.01f * s);
  const float aT = aPre[b * NP1 + NN];
  const float ak = aPre[b * NP1 + k];
  const float bk = bPre[b * NP1 + k];
  const float inv = 1.0f / (w1 * (aT - ak) + w2 * bk);
  const int o = threadIdx.x;
  const unsigned uk = P12[((size_t)b * NP1 + k) * FOUT + o];
  const unsigned uT = P12[((size_t)b * NP1 + NN) * FOUT + o];
  float num = w1 * (lo2f(uT) - lo2f(uk)) + w2 * hi2f(uk);
  out[(size_t)row * FOUT + o] = num * inv;
}

extern "C" void kernel_launch(void* const* d_in, const int* in_sizes, int n_in,
                              void* d_out, int out_size, void* d_ws, size_t ws_size,
                              hipStream_t stream){
  const float* h  = (const float*)d_in[0];
  const float* W  = (const float*)d_in[1];
  const float* ai = (const float*)d_in[2];
  const float* aj = (const float*)d_in[3];
  float* out = (float*)d_out;

  char* ws = (char*)d_ws;
  size_t off = 0;
  auto alloc = [&](size_t bytes) -> void* {
    void* p = ws + off;
    off += (bytes + 255) & ~(size_t)255;
    return p;
  };
  float*    Wh       = (float*)   alloc((size_t)ROWS * FOUT * 4);        // 8 MB
  float*    sI       = (float*)   alloc((size_t)ROWS * 4);
  float*    sJ       = (float*)   alloc((size_t)ROWS * 4);
  float*    sortedS  = (float*)   alloc((size_t)BATCH * NN * 4);
  int*      perm     = (int*)     alloc((size_t)BATCH * NN * 4);
  float*    e1       = (float*)   alloc((size_t)BATCH * NN * 4);
  float*    e2       = (float*)   alloc((size_t)BATCH * NN * 4);
  float*    aPre     = (float*)   alloc((size_t)BATCH * NP1 * 4);
  float*    bPre     = (float*)   alloc((size_t)BATCH * NP1 * 4);
  unsigned* P12      = (unsigned*)alloc((size_t)BATCH * NP1 * FOUT * 4); // 8.4 MB

  k_gemm        <<<ROWS / 32, 256, 0, stream>>>(h, W, ai, aj, Wh, sI, sJ);
  k_rank_scatter<<<BATCH * 32, 256, 0, stream>>>(sJ, sortedS, perm, e1, e2);
  k_fuse        <<<BATCH + BATCH * 32, 256, 0, stream>>>(e1, e2, Wh, perm, aPre, bPre, P12);
  k_out         <<<ROWS, 128, 0, stream>>>(sI, sortedS, aPre, bPre, P12, out);
}

// Round 4
// 131.901 us; speedup vs baseline: 2.2984x; 1.0259x over previous
//
#include <hip/hip_runtime.h>
#include <hip/hip_bf16.h>

#define BATCH 8
#define NN 2048
#define FIN 256
#define FOUT 128
#define ROWS (BATCH*NN)
#define NP1 (NN+1)
#define SEGS 64          // row segments per batch in k_fuse
#define SLEN (NN/SEGS)   // 32 rows per segment

typedef __attribute__((ext_vector_type(8))) __bf16 bf16x8;
typedef __attribute__((ext_vector_type(4))) float f32x4;
typedef __attribute__((ext_vector_type(8))) unsigned short ushort8_t;

__device__ __forceinline__ unsigned pack2(float a, float b){
  __hip_bfloat16 x = __float2bfloat16(a), y = __float2bfloat16(b);
  unsigned short ux = *(unsigned short*)&x, uy = *(unsigned short*)&y;
  return ((unsigned)uy << 16) | (unsigned)ux;
}
__device__ __forceinline__ float lo2f(unsigned u){ union{unsigned v;float f;}c; c.v = u << 16; return c.f; }
__device__ __forceinline__ float hi2f(unsigned u){ union{unsigned v;float f;}c; c.v = u & 0xffff0000u; return c.f; }

// split x into bf16 hi + bf16 lo (x ≈ hi + lo, error ~2^-17 relative)
__device__ __forceinline__ void bsplit(float x, unsigned short& hu, unsigned short& lu){
  __hip_bfloat16 hb = __float2bfloat16(x);
  hu = *(unsigned short*)&hb;
  union{unsigned u; float f;} hf; hf.u = (unsigned)hu << 16;
  __hip_bfloat16 lb = __float2bfloat16(x - hf.f);
  lu = *(unsigned short*)&lb;
}

// ---------------- K0: split W -> transposed bf16 hi/lo [col][k] (128 KB once) ----
__global__ __launch_bounds__(256) void k_wsplit(const float* __restrict__ W,
                                                unsigned short* __restrict__ Wth,
                                                unsigned short* __restrict__ Wtl){
  const int gid = blockIdx.x * 256 + threadIdx.x;   // 0..8191
  const int k = gid >> 5, c4 = (gid & 31) * 4;
  float4 v = *(const float4*)&W[(size_t)k * FOUT + c4];
  float xs[4] = {v.x, v.y, v.z, v.w};
  #pragma unroll
  for (int i = 0; i < 4; i++){
    unsigned short hu, lu;
    bsplit(xs[i], hu, lu);
    Wth[(size_t)(c4 + i) * FIN + k] = hu;
    Wtl[(size_t)(c4 + i) * FIN + k] = lu;
  }
}

// ---------------- K1: MFMA split-bf16 Wh = h @ W + fused s_i/s_j ----------------
// 32-row x 128-col block tile, 512 blocks x 256 thr (2 blocks/CU, 2 waves/SIMD).
// Wave w: rows (w&1)*16..+15, cols (w>>1)*64..+63 (4 16x16 tiles).
// LDS rows padded to 80 B -> all fragment ds_read_b128 bank-uniform.
// k-order bijection identical for A and B frags -> layout-proof correctness.
__global__ __launch_bounds__(256) void k_gemm(const float* __restrict__ h,
                                              const unsigned short* __restrict__ Wth,
                                              const unsigned short* __restrict__ Wtl,
                                              const float* __restrict__ ai,
                                              const float* __restrict__ aj,
                                              float* __restrict__ Wh,
                                              float* __restrict__ sI,
                                              float* __restrict__ sJ){
  __shared__ unsigned short Ah[32*40], Al[32*40];     // [row][k] pad 40 ushort (80 B)
  __shared__ unsigned short Bh[128*40], Bl[128*40];   // [col][k] pad 40
  __shared__ float spI[2][32], spJ[2][32];
  const int t = threadIdx.x;
  const int rbase = blockIdx.x * 32;
  const int w = t >> 6, l = t & 63;
  const int g = w & 1, cg = w >> 1;       // row-half, col-group(64)
  const int lr = l & 15, lq = l >> 4;     // M/N low index, k-quarter
  const int sar = t >> 3, sak = (t & 7) * 4;   // A staging: row, k-off (4 floats)
  const int sbc = t >> 1, sbh = (t & 1) * 16;  // B staging: col, k-half

  f32x4 acc[4];
  #pragma unroll
  for (int ct = 0; ct < 4; ct++) acc[ct] = (f32x4){0.f, 0.f, 0.f, 0.f};

  for (int k0 = 0; k0 < FIN; k0 += 32){
    // --- A stage: load float4 of h, split, write bf16x4 hi/lo ---
    {
      float4 hv = *(const float4*)&h[(size_t)(rbase + sar) * FIN + k0 + sak];
      float xs[4] = {hv.x, hv.y, hv.z, hv.w};
      ushort4 hh, ll;
      unsigned short hu, lu;
      bsplit(xs[0], hu, lu); hh.x = hu; ll.x = lu;
      bsplit(xs[1], hu, lu); hh.y = hu; ll.y = lu;
      bsplit(xs[2], hu, lu); hh.z = hu; ll.z = lu;
      bsplit(xs[3], hu, lu); hh.w = hu; ll.w = lu;
      *(ushort4*)&Ah[sar * 40 + sak] = hh;
      *(ushort4*)&Al[sar * 40 + sak] = ll;
    }
    // --- B stage: copy pre-split Wt hi/lo (coalesced 16B chunks) ---
    {
      const size_t gb = (size_t)sbc * FIN + k0 + sbh;
      ushort8_t b0 = *(const ushort8_t*)&Wth[gb];
      ushort8_t b1 = *(const ushort8_t*)&Wth[gb + 8];
      ushort8_t c0 = *(const ushort8_t*)&Wtl[gb];
      ushort8_t c1 = *(const ushort8_t*)&Wtl[gb + 8];
      *(ushort8_t*)&Bh[sbc * 40 + sbh]     = b0;
      *(ushort8_t*)&Bh[sbc * 40 + sbh + 8] = b1;
      *(ushort8_t*)&Bl[sbc * 40 + sbh]     = c0;
      *(ushort8_t*)&Bl[sbc * 40 + sbh + 8] = c1;
    }
    __syncthreads();
    const bf16x8 avh = __builtin_bit_cast(bf16x8, *(const ushort8_t*)&Ah[(g*16 + lr)*40 + lq*8]);
    const bf16x8 avl = __builtin_bit_cast(bf16x8, *(const ushort8_t*)&Al[(g*16 + lr)*40 + lq*8]);
    #pragma unroll
    for (int ct = 0; ct < 4; ct++){
      const int col = cg*64 + ct*16 + lr;
      const bf16x8 bvh = __builtin_bit_cast(bf16x8, *(const ushort8_t*)&Bh[col*40 + lq*8]);
      const bf16x8 bvl = __builtin_bit_cast(bf16x8, *(const ushort8_t*)&Bl[col*40 + lq*8]);
      acc[ct] = __builtin_amdgcn_mfma_f32_16x16x32_bf16(avh, bvh, acc[ct], 0, 0, 0);
      acc[ct] = __builtin_amdgcn_mfma_f32_16x16x32_bf16(avh, bvl, acc[ct], 0, 0, 0);
      acc[ct] = __builtin_amdgcn_mfma_f32_16x16x32_bf16(avl, bvh, acc[ct], 0, 0, 0);
    }
    __syncthreads();
  }
  // --- epilogue: store Wh, fused s_i/s_j ---
  float pi[4] = {0.f,0.f,0.f,0.f}, pj[4] = {0.f,0.f,0.f,0.f};
  #pragma unroll
  for (int ct = 0; ct < 4; ct++){
    const int col = cg*64 + ct*16 + lr;
    const float fai = ai[col], faj = aj[col];
    #pragma unroll
    for (int q = 0; q < 4; q++){
      const float val = acc[ct][q];
      Wh[(size_t)(rbase + g*16 + lq*4 + q) * FOUT + col] = val;
      pi[q] = fmaf(val, fai, pi[q]);
      pj[q] = fmaf(val, faj, pj[q]);
    }
  }
  #pragma unroll
  for (int q = 0; q < 4; q++){
    #pragma unroll
    for (int m = 1; m < 16; m <<= 1){
      pi[q] += __shfl_xor(pi[q], m);
      pj[q] += __shfl_xor(pj[q], m);
    }
  }
  if (lr == 0){
    #pragma unroll
    for (int q = 0; q < 4; q++){
      spI[cg][g*16 + lq*4 + q] = pi[q];
      spJ[cg][g*16 + lq*4 + q] = pj[q];
    }
  }
  __syncthreads();
  if (t < 32){
    sI[rbase + t] = spI[0][t] + spI[1][t];
    sJ[rbase + t] = spJ[0][t] + spJ[1][t];
  }
}

// ---------------- K2: one-shot rank + scatter (r3-proven) ----------
__global__ __launch_bounds__(256) void k_rank_scatter(const float* __restrict__ sJ,
                                                      float* __restrict__ sortedS,
                                                      int* __restrict__ perm,
                                                      float* __restrict__ e1g,
                                                      float* __restrict__ e2g){
  const int b = blockIdx.x >> 5;        // 32 blocks per batch
  const int jc = blockIdx.x & 31;       // 64 j's per block
  __shared__ float v[NN];               // 8 KB
  __shared__ int partial[4][64];
  const int t = threadIdx.x;
  const float* sj = sJ + b * NN;
  for (int u = t; u < NN; u += 256) v[u] = sj[u];
  const int jj = t & 63, qq = t >> 6;
  const int j = jc * 64 + jj;
  const float x = sj[j];
  __syncthreads();
  const int q0 = qq * 512;
  int r = 0;
  #pragma unroll 8
  for (int q4 = 0; q4 < 128; q4++){
    const int q = q0 + q4 * 4;
    float4 y = *(const float4*)&v[q];
    r += (y.x < x) || (y.x == x && (q + 0) < j);
    r += (y.y < x) || (y.y == x && (q + 1) < j);
    r += (y.z < x) || (y.z == x && (q + 2) < j);
    r += (y.w < x) || (y.w == x && (q + 3) < j);
  }
  partial[qq][jj] = r;
  __syncthreads();
  if (t < 64){
    const int R = partial[0][t] + partial[1][t] + partial[2][t] + partial[3][t];
    const int myj = jc * 64 + t;
    const float xx = v[myj];
    sortedS[b * NN + R] = xx;
    perm[b * NN + R] = myj;
    e1g[b * NN + R] = expf(xx);
    e2g[b * NN + R] = expf(0.01f * xx);
  }
}

// ---------------- K3: fused scans (r3-proven) -------------
__global__ __launch_bounds__(256) void k_fuse(const float* __restrict__ e1g,
                                              const float* __restrict__ e2g,
                                              const float* __restrict__ Wh,
                                              const int* __restrict__ perm,
                                              float* __restrict__ aPre,
                                              float* __restrict__ bPre,
                                              unsigned* __restrict__ P12){
  const int t = threadIdx.x;
  if (blockIdx.x < BATCH){
    const int b = blockIdx.x;
    __shared__ float p1[256], p2[256];
    __shared__ float x1[256], x2[256];
    const float* e1 = e1g + b * NN;
    const float* e2 = e2g + b * NN;
    float l1[8], l2[8];
    float s1 = 0.f, s2 = 0.f;
    #pragma unroll
    for (int q = 0; q < 8; q++){
      s1 += e1[t * 8 + q]; l1[q] = s1;
      s2 += e2[t * 8 + q]; l2[q] = s2;
    }
    p1[t] = s1; p2[t] = s2;
    __syncthreads();
    if (t == 0){
      float a = 0.f, c = 0.f;
      for (int q = 0; q < 256; q++){
        x1[q] = a; a += p1[q];
        x2[q] = c; c += p2[q];
      }
    }
    __syncthreads();
    const float b1 = x1[t], b2 = x2[t];
    float* aP = aPre + b * NP1;
    float* bP = bPre + b * NP1;
    #pragma unroll
    for (int q = 0; q < 8; q++){
      aP[1 + t * 8 + q] = b1 + l1[q];
      bP[1 + t * 8 + q] = b2 + l2[q];
    }
    if (t == 0){ aP[0] = 0.f; bP[0] = 0.f; }
    return;
  }
  // ---- fused column scan ----
  const int bc = blockIdx.x - BATCH;    // 0..255
  const int b = bc >> 5;                // 32 blocks per batch
  const int og = bc & 31;               // 4 output cols each
  const int ol = t & 3;
  const int o = og * 4 + ol;
  const int seg = t >> 2;               // 0..63
  const int r0 = seg * SLEN;
  __shared__ float p1[SEGS][4], p2[SEGS][4];
  const int*   pm  = perm + b * NN;
  const float* e1  = e1g  + b * NN;
  const float* e2  = e2g  + b * NN;
  const float* whb = Wh + (size_t)b * NN * FOUT;
  float w[SLEN];
  float t1 = 0.f, t2 = 0.f;
  #pragma unroll
  for (int r = 0; r < SLEN; r++){       // full unroll: static w[] indices
    w[r] = whb[(size_t)pm[r0 + r] * FOUT + o];
    const float u1 = e1[r0 + r], u2 = e2[r0 + r];
    t1 = fmaf(u1, w[r], t1);
    t2 = fmaf(u2, w[r], t2);
  }
  p1[seg][ol] = t1; p2[seg][ol] = t2;
  __syncthreads();
  #pragma unroll
  for (int d = 1; d < SEGS; d <<= 1){   // inclusive Hillis-Steele over segs
    const float u1 = (seg >= d) ? p1[seg - d][ol] : 0.f;
    const float u2 = (seg >= d) ? p2[seg - d][ol] : 0.f;
    __syncthreads();
    if (seg >= d){ p1[seg][ol] += u1; p2[seg][ol] += u2; }
    __syncthreads();
  }
  float acc1 = p1[seg][ol] - t1;        // exclusive offset
  float acc2 = p2[seg][ol] - t2;
  unsigned* pp = P12 + (size_t)b * NP1 * FOUT + o;
  if (seg == 0) pp[0] = 0u;
  #pragma unroll
  for (int r = 0; r < SLEN; r++){
    acc1 = fmaf(e1[r0 + r], w[r], acc1);
    acc2 = fmaf(e2[r0 + r], w[r], acc2);
    pp[(size_t)(r0 + r + 1) * FOUT] = pack2(acc1, acc2);
  }
}

// ---------------- K4: per-row combine, fp32 store (r3-proven) ----------------
__global__ __launch_bounds__(128) void k_out(const float* __restrict__ sI,
                                             const float* __restrict__ sortedS,
                                             const float* __restrict__ aPre,
                                             const float* __restrict__ bPre,
                                             const unsigned* __restrict__ P12,
                                             float* __restrict__ out){
  const int row = blockIdx.x;
  const int b = row >> 11;
  const float s = sI[row];
  const float key = -s;
  const float* ss = sortedS + b * NN;
  int lo = 0, hi = NN;
  while (lo < hi){
    int mid = (lo + hi) >> 1;
    if (ss[mid] <= key) lo = mid + 1; else hi = mid;
  }
  const int k = lo;
  const float w1 = expf(s), w2 = expf(0.01f * s);
  const float aT = aPre[b * NP1 + NN];
  const float ak = aPre[b * NP1 + k];
  const float bk = bPre[b * NP1 + k];
  const float inv = 1.0f / (w1 * (aT - ak) + w2 * bk);
  const int o = threadIdx.x;
  const unsigned uk = P12[((size_t)b * NP1 + k) * FOUT + o];
  const unsigned uT = P12[((size_t)b * NP1 + NN) * FOUT + o];
  float num = w1 * (lo2f(uT) - lo2f(uk)) + w2 * hi2f(uk);
  out[(size_t)row * FOUT + o] = num * inv;
}

extern "C" void kernel_launch(void* const* d_in, const int* in_sizes, int n_in,
                              void* d_out, int out_size, void* d_ws, size_t ws_size,
                              hipStream_t stream){
  const float* h  = (const float*)d_in[0];
  const float* W  = (const float*)d_in[1];
  const float* ai = (const float*)d_in[2];
  const float* aj = (const float*)d_in[3];
  float* out = (float*)d_out;

  char* ws = (char*)d_ws;
  size_t off = 0;
  auto alloc = [&](size_t bytes) -> void* {
    void* p = ws + off;
    off += (bytes + 255) & ~(size_t)255;
    return p;
  };
  float*          Wh   = (float*)   alloc((size_t)ROWS * FOUT * 4);        // 8 MB
  float*          sI   = (float*)   alloc((size_t)ROWS * 4);
  float*          sJ   = (float*)   alloc((size_t)ROWS * 4);
  float*          sortedS = (float*)alloc((size_t)BATCH * NN * 4);
  int*            perm = (int*)     alloc((size_t)BATCH * NN * 4);
  float*          e1   = (float*)   alloc((size_t)BATCH * NN * 4);
  float*          e2   = (float*)   alloc((size_t)BATCH * NN * 4);
  float*          aPre = (float*)   alloc((size_t)BATCH * NP1 * 4);
  float*          bPre = (float*)   alloc((size_t)BATCH * NP1 * 4);
  unsigned*       P12  = (unsigned*)alloc((size_t)BATCH * NP1 * FOUT * 4); // 8.4 MB
  unsigned short* Wth  = (unsigned short*)alloc((size_t)FOUT * FIN * 2);   // 64 KB
  unsigned short* Wtl  = (unsigned short*)alloc((size_t)FOUT * FIN * 2);   // 64 KB

  k_wsplit      <<<32, 256, 0, stream>>>(W, Wth, Wtl);
  k_gemm        <<<ROWS / 32, 256, 0, stream>>>(h, Wth, Wtl, ai, aj, Wh, sI, sJ);
  k_rank_scatter<<<BATCH * 32, 256, 0, stream>>>(sJ, sortedS, perm, e1, e2);
  k_fuse        <<<BATCH + BATCH * 32, 256, 0, stream>>>(e1, e2, Wh, perm, aPre, bPre, P12);
  k_out         <<<ROWS, 128, 0, stream>>>(sI, sortedS, aPre, bPre, P12, out);
}

// Round 5
// 127.281 us; speedup vs baseline: 2.3818x; 1.0363x over previous
//
#include <hip/hip_runtime.h>
#include <hip/hip_bf16.h>

#define BATCH 8
#define NN 2048
#define FIN 256
#define FOUT 128
#define ROWS (BATCH*NN)
#define NP1 (NN+1)
#define SEGS 128         // row segments per batch in k_fuse
#define SLEN (NN/SEGS)   // 16 rows per segment

typedef __attribute__((ext_vector_type(8))) __bf16 bf16x8;
typedef __attribute__((ext_vector_type(4))) float f32x4;
typedef __attribute__((ext_vector_type(8))) unsigned short ushort8_t;

__device__ __forceinline__ unsigned pack2(float a, float b){
  __hip_bfloat16 x = __float2bfloat16(a), y = __float2bfloat16(b);
  unsigned short ux = *(unsigned short*)&x, uy = *(unsigned short*)&y;
  return ((unsigned)uy << 16) | (unsigned)ux;
}
__device__ __forceinline__ float lo2f(unsigned u){ union{unsigned v;float f;}c; c.v = u << 16; return c.f; }
__device__ __forceinline__ float hi2f(unsigned u){ union{unsigned v;float f;}c; c.v = u & 0xffff0000u; return c.f; }

// split x into bf16 hi + bf16 lo (x ≈ hi + lo, error ~2^-17 relative)
__device__ __forceinline__ void bsplit(float x, unsigned short& hu, unsigned short& lu){
  __hip_bfloat16 hb = __float2bfloat16(x);
  hu = *(unsigned short*)&hb;
  union{unsigned u; float f;} hf; hf.u = (unsigned)hu << 16;
  __hip_bfloat16 lb = __float2bfloat16(x - hf.f);
  lu = *(unsigned short*)&lb;
}

// ---------------- K0: split W -> transposed bf16 hi/lo [col][k] (r4-proven) ----
__global__ __launch_bounds__(256) void k_wsplit(const float* __restrict__ W,
                                                unsigned short* __restrict__ Wth,
                                                unsigned short* __restrict__ Wtl){
  const int gid = blockIdx.x * 256 + threadIdx.x;   // 0..8191
  const int k = gid >> 5, c4 = (gid & 31) * 4;
  float4 v = *(const float4*)&W[(size_t)k * FOUT + c4];
  float xs[4] = {v.x, v.y, v.z, v.w};
  #pragma unroll
  for (int i = 0; i < 4; i++){
    unsigned short hu, lu;
    bsplit(xs[i], hu, lu);
    Wth[(size_t)(c4 + i) * FIN + k] = hu;
    Wtl[(size_t)(c4 + i) * FIN + k] = lu;
  }
}

// ---------------- K1: MFMA split-bf16 Wh = h @ W + fused s_i/s_j (r4-proven) ----
__global__ __launch_bounds__(256) void k_gemm(const float* __restrict__ h,
                                              const unsigned short* __restrict__ Wth,
                                              const unsigned short* __restrict__ Wtl,
                                              const float* __restrict__ ai,
                                              const float* __restrict__ aj,
                                              float* __restrict__ Wh,
                                              float* __restrict__ sI,
                                              float* __restrict__ sJ){
  __shared__ unsigned short Ah[32*40], Al[32*40];     // [row][k] pad 40 ushort (80 B)
  __shared__ unsigned short Bh[128*40], Bl[128*40];   // [col][k] pad 40
  __shared__ float spI[2][32], spJ[2][32];
  const int t = threadIdx.x;
  const int rbase = blockIdx.x * 32;
  const int w = t >> 6, l = t & 63;
  const int g = w & 1, cg = w >> 1;       // row-half, col-group(64)
  const int lr = l & 15, lq = l >> 4;     // M/N low index, k-quarter
  const int sar = t >> 3, sak = (t & 7) * 4;   // A staging: row, k-off (4 floats)
  const int sbc = t >> 1, sbh = (t & 1) * 16;  // B staging: col, k-half

  f32x4 acc[4];
  #pragma unroll
  for (int ct = 0; ct < 4; ct++) acc[ct] = (f32x4){0.f, 0.f, 0.f, 0.f};

  for (int k0 = 0; k0 < FIN; k0 += 32){
    {
      float4 hv = *(const float4*)&h[(size_t)(rbase + sar) * FIN + k0 + sak];
      float xs[4] = {hv.x, hv.y, hv.z, hv.w};
      ushort4 hh, ll;
      unsigned short hu, lu;
      bsplit(xs[0], hu, lu); hh.x = hu; ll.x = lu;
      bsplit(xs[1], hu, lu); hh.y = hu; ll.y = lu;
      bsplit(xs[2], hu, lu); hh.z = hu; ll.z = lu;
      bsplit(xs[3], hu, lu); hh.w = hu; ll.w = lu;
      *(ushort4*)&Ah[sar * 40 + sak] = hh;
      *(ushort4*)&Al[sar * 40 + sak] = ll;
    }
    {
      const size_t gb = (size_t)sbc * FIN + k0 + sbh;
      ushort8_t b0 = *(const ushort8_t*)&Wth[gb];
      ushort8_t b1 = *(const ushort8_t*)&Wth[gb + 8];
      ushort8_t c0 = *(const ushort8_t*)&Wtl[gb];
      ushort8_t c1 = *(const ushort8_t*)&Wtl[gb + 8];
      *(ushort8_t*)&Bh[sbc * 40 + sbh]     = b0;
      *(ushort8_t*)&Bh[sbc * 40 + sbh + 8] = b1;
      *(ushort8_t*)&Bl[sbc * 40 + sbh]     = c0;
      *(ushort8_t*)&Bl[sbc * 40 + sbh + 8] = c1;
    }
    __syncthreads();
    const bf16x8 avh = __builtin_bit_cast(bf16x8, *(const ushort8_t*)&Ah[(g*16 + lr)*40 + lq*8]);
    const bf16x8 avl = __builtin_bit_cast(bf16x8, *(const ushort8_t*)&Al[(g*16 + lr)*40 + lq*8]);
    #pragma unroll
    for (int ct = 0; ct < 4; ct++){
      const int col = cg*64 + ct*16 + lr;
      const bf16x8 bvh = __builtin_bit_cast(bf16x8, *(const ushort8_t*)&Bh[col*40 + lq*8]);
      const bf16x8 bvl = __builtin_bit_cast(bf16x8, *(const ushort8_t*)&Bl[col*40 + lq*8]);
      acc[ct] = __builtin_amdgcn_mfma_f32_16x16x32_bf16(avh, bvh, acc[ct], 0, 0, 0);
      acc[ct] = __builtin_amdgcn_mfma_f32_16x16x32_bf16(avh, bvl, acc[ct], 0, 0, 0);
      acc[ct] = __builtin_amdgcn_mfma_f32_16x16x32_bf16(avl, bvh, acc[ct], 0, 0, 0);
    }
    __syncthreads();
  }
  float pi[4] = {0.f,0.f,0.f,0.f}, pj[4] = {0.f,0.f,0.f,0.f};
  #pragma unroll
  for (int ct = 0; ct < 4; ct++){
    const int col = cg*64 + ct*16 + lr;
    const float fai = ai[col], faj = aj[col];
    #pragma unroll
    for (int q = 0; q < 4; q++){
      const float val = acc[ct][q];
      Wh[(size_t)(rbase + g*16 + lq*4 + q) * FOUT + col] = val;
      pi[q] = fmaf(val, fai, pi[q]);
      pj[q] = fmaf(val, faj, pj[q]);
    }
  }
  #pragma unroll
  for (int q = 0; q < 4; q++){
    #pragma unroll
    for (int m = 1; m < 16; m <<= 1){
      pi[q] += __shfl_xor(pi[q], m);
      pj[q] += __shfl_xor(pj[q], m);
    }
  }
  if (lr == 0){
    #pragma unroll
    for (int q = 0; q < 4; q++){
      spI[cg][g*16 + lq*4 + q] = pi[q];
      spJ[cg][g*16 + lq*4 + q] = pj[q];
    }
  }
  __syncthreads();
  if (t < 32){
    sI[rbase + t] = spI[0][t] + spI[1][t];
    sJ[rbase + t] = spJ[0][t] + spJ[1][t];
  }
}

// ---------------- K2: one-shot rank + scatter, 2 blocks/CU ----------
// 512 blocks: (b, 32 j's). Full sJ[b] in LDS; thread (jj,qq) compares j
// against a 256-wide q-octant; reduce 8 partials -> exact rank -> scatter.
__global__ __launch_bounds__(256) void k_rank_scatter(const float* __restrict__ sJ,
                                                      float* __restrict__ sortedS,
                                                      int* __restrict__ perm,
                                                      float* __restrict__ e1g,
                                                      float* __restrict__ e2g){
  const int b = blockIdx.x >> 6;        // 64 blocks per batch
  const int jc = blockIdx.x & 63;       // 32 j's per block
  __shared__ float v[NN];               // 8 KB
  __shared__ int partial[8][32];
  const int t = threadIdx.x;
  const float* sj = sJ + b * NN;
  #pragma unroll
  for (int u = 0; u < 2; u++)
    ((float4*)v)[t + u * 256] = ((const float4*)sj)[t + u * 256];
  const int jj = t & 31, qq = t >> 5;
  const int j = jc * 32 + jj;
  const float x = sj[j];
  __syncthreads();
  const int q0 = qq * 256;
  int r = 0;
  #pragma unroll 8
  for (int q4 = 0; q4 < 64; q4++){
    const int q = q0 + q4 * 4;
    float4 y = *(const float4*)&v[q];
    r += (y.x < x) || (y.x == x && (q + 0) < j);
    r += (y.y < x) || (y.y == x && (q + 1) < j);
    r += (y.z < x) || (y.z == x && (q + 2) < j);
    r += (y.w < x) || (y.w == x && (q + 3) < j);
  }
  partial[qq][jj] = r;
  __syncthreads();
  if (t < 32){
    int R = 0;
    #pragma unroll
    for (int q8 = 0; q8 < 8; q8++) R += partial[q8][t];
    const int myj = jc * 32 + t;
    const float xx = v[myj];
    sortedS[b * NN + R] = xx;
    perm[b * NN + R] = myj;
    e1g[b * NN + R] = expf(xx);
    e2g[b * NN + R] = expf(0.01f * xx);
  }
}

// ---------------- K3: fused scans, 512-thread blocks (2 waves/SIMD) -------------
// Blocks 0-7: parallel Hillis-Steele e-prefix sums -> aPre/bPre.
// Blocks 8-263: (b, 4-output-cols). Thread (ol, seg of 128): gather 16 Wh values
// once into regs, per-seg totals -> HS prefix over 128 segs -> write P12.
__global__ __launch_bounds__(512) void k_fuse(const float* __restrict__ e1g,
                                              const float* __restrict__ e2g,
                                              const float* __restrict__ Wh,
                                              const int* __restrict__ perm,
                                              float* __restrict__ aPre,
                                              float* __restrict__ bPre,
                                              unsigned* __restrict__ P12){
  const int t = threadIdx.x;
  if (blockIdx.x < BATCH){
    // ---- scalar e-prefix sums, fully parallel (4 elems/thread, HS over 512) ----
    const int b = blockIdx.x;
    __shared__ float p1[512], p2[512];
    const float* e1 = e1g + b * NN;
    const float* e2 = e2g + b * NN;
    float l1[4], l2[4];
    float s1 = 0.f, s2 = 0.f;
    #pragma unroll
    for (int q = 0; q < 4; q++){
      s1 += e1[t * 4 + q]; l1[q] = s1;
      s2 += e2[t * 4 + q]; l2[q] = s2;
    }
    p1[t] = s1; p2[t] = s2;
    __syncthreads();
    #pragma unroll
    for (int d = 1; d < 512; d <<= 1){
      const float u1 = (t >= d) ? p1[t - d] : 0.f;
      const float u2 = (t >= d) ? p2[t - d] : 0.f;
      __syncthreads();
      if (t >= d){ p1[t] += u1; p2[t] += u2; }
      __syncthreads();
    }
    const float b1 = p1[t] - s1, b2 = p2[t] - s2;   // exclusive offset
    float* aP = aPre + b * NP1;
    float* bP = bPre + b * NP1;
    #pragma unroll
    for (int q = 0; q < 4; q++){
      aP[1 + t * 4 + q] = b1 + l1[q];
      bP[1 + t * 4 + q] = b2 + l2[q];
    }
    if (t == 0){ aP[0] = 0.f; bP[0] = 0.f; }
    return;
  }
  // ---- fused column scan ----
  const int bc = blockIdx.x - BATCH;    // 0..255
  const int b = bc >> 5;                // 32 blocks per batch
  const int og = bc & 31;               // 4 output cols each
  const int ol = t & 3;
  const int o = og * 4 + ol;
  const int seg = t >> 2;               // 0..127
  const int r0 = seg * SLEN;
  __shared__ float p1[SEGS][4], p2[SEGS][4];
  const int*   pm  = perm + b * NN;
  const float* e1  = e1g  + b * NN;
  const float* e2  = e2g  + b * NN;
  const float* whb = Wh + (size_t)b * NN * FOUT;
  float w[SLEN];
  float t1 = 0.f, t2 = 0.f;
  #pragma unroll
  for (int r = 0; r < SLEN; r++){       // full unroll: static w[] indices
    w[r] = whb[(size_t)pm[r0 + r] * FOUT + o];
    const float u1 = e1[r0 + r], u2 = e2[r0 + r];
    t1 = fmaf(u1, w[r], t1);
    t2 = fmaf(u2, w[r], t2);
  }
  p1[seg][ol] = t1; p2[seg][ol] = t2;
  __syncthreads();
  #pragma unroll
  for (int d = 1; d < SEGS; d <<= 1){   // inclusive HS over 128 segs
    const float u1 = (seg >= d) ? p1[seg - d][ol] : 0.f;
    const float u2 = (seg >= d) ? p2[seg - d][ol] : 0.f;
    __syncthreads();
    if (seg >= d){ p1[seg][ol] += u1; p2[seg][ol] += u2; }
    __syncthreads();
  }
  float acc1 = p1[seg][ol] - t1;        // exclusive offset
  float acc2 = p2[seg][ol] - t2;
  unsigned* pp = P12 + (size_t)b * NP1 * FOUT + o;
  if (seg == 0) pp[0] = 0u;
  #pragma unroll
  for (int r = 0; r < SLEN; r++){
    acc1 = fmaf(e1[r0 + r], w[r], acc1);
    acc2 = fmaf(e2[r0 + r], w[r], acc2);
    pp[(size_t)(r0 + r + 1) * FOUT] = pack2(acc1, acc2);
  }
}

// ---------------- K4: per-row combine, 2 rows per block ----------------
__global__ __launch_bounds__(256) void k_out(const float* __restrict__ sI,
                                             const float* __restrict__ sortedS,
                                             const float* __restrict__ aPre,
                                             const float* __restrict__ bPre,
                                             const unsigned* __restrict__ P12,
                                             float* __restrict__ out){
  const int row = blockIdx.x * 2 + (threadIdx.x >> 7);
  const int b = row >> 11;
  const float s = sI[row];
  const float key = -s;
  const float* ss = sortedS + b * NN;
  int lo = 0, hi = NN;
  while (lo < hi){
    int mid = (lo + hi) >> 1;
    if (ss[mid] <= key) lo = mid + 1; else hi = mid;
  }
  const int k = lo;
  const float w1 = expf(s), w2 = expf(0.01f * s);
  const float aT = aPre[b * NP1 + NN];
  const float ak = aPre[b * NP1 + k];
  const float bk = bPre[b * NP1 + k];
  const float inv = 1.0f / (w1 * (aT - ak) + w2 * bk);
  const int o = threadIdx.x & 127;
  const unsigned uk = P12[((size_t)b * NP1 + k) * FOUT + o];
  const unsigned uT = P12[((size_t)b * NP1 + NN) * FOUT + o];
  float num = w1 * (lo2f(uT) - lo2f(uk)) + w2 * hi2f(uk);
  out[(size_t)row * FOUT + o] = num * inv;
}

extern "C" void kernel_launch(void* const* d_in, const int* in_sizes, int n_in,
                              void* d_out, int out_size, void* d_ws, size_t ws_size,
                              hipStream_t stream){
  const float* h  = (const float*)d_in[0];
  const float* W  = (const float*)d_in[1];
  const float* ai = (const float*)d_in[2];
  const float* aj = (const float*)d_in[3];
  float* out = (float*)d_out;

  char* ws = (char*)d_ws;
  size_t off = 0;
  auto alloc = [&](size_t bytes) -> void* {
    void* p = ws + off;
    off += (bytes + 255) & ~(size_t)255;
    return p;
  };
  float*          Wh   = (float*)   alloc((size_t)ROWS * FOUT * 4);        // 8 MB
  float*          sI   = (float*)   alloc((size_t)ROWS * 4);
  float*          sJ   = (float*)   alloc((size_t)ROWS * 4);
  float*          sortedS = (float*)alloc((size_t)BATCH * NN * 4);
  int*            perm = (int*)     alloc((size_t)BATCH * NN * 4);
  float*          e1   = (float*)   alloc((size_t)BATCH * NN * 4);
  float*          e2   = (float*)   alloc((size_t)BATCH * NN * 4);
  float*          aPre = (float*)   alloc((size_t)BATCH * NP1 * 4);
  float*          bPre = (float*)   alloc((size_t)BATCH * NP1 * 4);
  unsigned*       P12  = (unsigned*)alloc((size_t)BATCH * NP1 * FOUT * 4); // 8.4 MB
  unsigned short* Wth  = (unsigned short*)alloc((size_t)FOUT * FIN * 2);   // 64 KB
  unsigned short* Wtl  = (unsigned short*)alloc((size_t)FOUT * FIN * 2);   // 64 KB

  k_wsplit      <<<32, 256, 0, stream>>>(W, Wth, Wtl);
  k_gemm        <<<ROWS / 32, 256, 0, stream>>>(h, Wth, Wtl, ai, aj, Wh, sI, sJ);
  k_rank_scatter<<<BATCH * 64, 256, 0, stream>>>(sJ, sortedS, perm, e1, e2);
  k_fuse        <<<BATCH + BATCH * 32, 512, 0, stream>>>(e1, e2, Wh, perm, aPre, bPre, P12);
  k_out         <<<ROWS / 2, 256, 0, stream>>>(sI, sortedS, aPre, bPre, P12, out);
}

// Round 6
// 126.500 us; speedup vs baseline: 2.3965x; 1.0062x over previous
//
#include <hip/hip_runtime.h>
#include <hip/hip_bf16.h>

#define BATCH 8
#define NN 2048
#define FIN 256
#define FOUT 128
#define ROWS (BATCH*NN)
#define NP1 (NN+1)
#define SEGS 128         // row segments per batch in k_fuse
#define SLEN (NN/SEGS)   // 16 rows per segment

typedef __attribute__((ext_vector_type(8))) __bf16 bf16x8;
typedef __attribute__((ext_vector_type(4))) float f32x4;
typedef __attribute__((ext_vector_type(8))) unsigned short ushort8_t;

__device__ __forceinline__ unsigned pack2(float a, float b){
  __hip_bfloat16 x = __float2bfloat16(a), y = __float2bfloat16(b);
  unsigned short ux = *(unsigned short*)&x, uy = *(unsigned short*)&y;
  return ((unsigned)uy << 16) | (unsigned)ux;
}
__device__ __forceinline__ float lo2f(unsigned u){ union{unsigned v;float f;}c; c.v = u << 16; return c.f; }
__device__ __forceinline__ float hi2f(unsigned u){ union{unsigned v;float f;}c; c.v = u & 0xffff0000u; return c.f; }

// split x into bf16 hi + bf16 lo (x ≈ hi + lo, error ~2^-17 relative)
__device__ __forceinline__ void bsplit(float x, unsigned short& hu, unsigned short& lu){
  __hip_bfloat16 hb = __float2bfloat16(x);
  hu = *(unsigned short*)&hb;
  union{unsigned u; float f;} hf; hf.u = (unsigned)hu << 16;
  __hip_bfloat16 lb = __float2bfloat16(x - hf.f);
  lu = *(unsigned short*)&lb;
}

// ---------------- K0: split W -> transposed bf16 hi/lo [col][k] (r4-proven) ----
__global__ __launch_bounds__(256) void k_wsplit(const float* __restrict__ W,
                                                unsigned short* __restrict__ Wth,
                                                unsigned short* __restrict__ Wtl){
  const int gid = blockIdx.x * 256 + threadIdx.x;   // 0..8191
  const int k = gid >> 5, c4 = (gid & 31) * 4;
  float4 v = *(const float4*)&W[(size_t)k * FOUT + c4];
  float xs[4] = {v.x, v.y, v.z, v.w};
  #pragma unroll
  for (int i = 0; i < 4; i++){
    unsigned short hu, lu;
    bsplit(xs[i], hu, lu);
    Wth[(size_t)(c4 + i) * FIN + k] = hu;
    Wtl[(size_t)(c4 + i) * FIN + k] = lu;
  }
}

// ---------------- K1: MFMA split-bf16 Wh = h @ W + fused s_i/s_j (r4-proven) ----
__global__ __launch_bounds__(256) void k_gemm(const float* __restrict__ h,
                                              const unsigned short* __restrict__ Wth,
                                              const unsigned short* __restrict__ Wtl,
                                              const float* __restrict__ ai,
                                              const float* __restrict__ aj,
                                              float* __restrict__ Wh,
                                              float* __restrict__ sI,
                                              float* __restrict__ sJ){
  __shared__ unsigned short Ah[32*40], Al[32*40];     // [row][k] pad 40 ushort (80 B)
  __shared__ unsigned short Bh[128*40], Bl[128*40];   // [col][k] pad 40
  __shared__ float spI[2][32], spJ[2][32];
  const int t = threadIdx.x;
  const int rbase = blockIdx.x * 32;
  const int w = t >> 6, l = t & 63;
  const int g = w & 1, cg = w >> 1;       // row-half, col-group(64)
  const int lr = l & 15, lq = l >> 4;     // M/N low index, k-quarter
  const int sar = t >> 3, sak = (t & 7) * 4;   // A staging: row, k-off (4 floats)
  const int sbc = t >> 1, sbh = (t & 1) * 16;  // B staging: col, k-half

  f32x4 acc[4];
  #pragma unroll
  for (int ct = 0; ct < 4; ct++) acc[ct] = (f32x4){0.f, 0.f, 0.f, 0.f};

  for (int k0 = 0; k0 < FIN; k0 += 32){
    {
      float4 hv = *(const float4*)&h[(size_t)(rbase + sar) * FIN + k0 + sak];
      float xs[4] = {hv.x, hv.y, hv.z, hv.w};
      ushort4 hh, ll;
      unsigned short hu, lu;
      bsplit(xs[0], hu, lu); hh.x = hu; ll.x = lu;
      bsplit(xs[1], hu, lu); hh.y = hu; ll.y = lu;
      bsplit(xs[2], hu, lu); hh.z = hu; ll.z = lu;
      bsplit(xs[3], hu, lu); hh.w = hu; ll.w = lu;
      *(ushort4*)&Ah[sar * 40 + sak] = hh;
      *(ushort4*)&Al[sar * 40 + sak] = ll;
    }
    {
      const size_t gb = (size_t)sbc * FIN + k0 + sbh;
      ushort8_t b0 = *(const ushort8_t*)&Wth[gb];
      ushort8_t b1 = *(const ushort8_t*)&Wth[gb + 8];
      ushort8_t c0 = *(const ushort8_t*)&Wtl[gb];
      ushort8_t c1 = *(const ushort8_t*)&Wtl[gb + 8];
      *(ushort8_t*)&Bh[sbc * 40 + sbh]     = b0;
      *(ushort8_t*)&Bh[sbc * 40 + sbh + 8] = b1;
      *(ushort8_t*)&Bl[sbc * 40 + sbh]     = c0;
      *(ushort8_t*)&Bl[sbc * 40 + sbh + 8] = c1;
    }
    __syncthreads();
    const bf16x8 avh = __builtin_bit_cast(bf16x8, *(const ushort8_t*)&Ah[(g*16 + lr)*40 + lq*8]);
    const bf16x8 avl = __builtin_bit_cast(bf16x8, *(const ushort8_t*)&Al[(g*16 + lr)*40 + lq*8]);
    #pragma unroll
    for (int ct = 0; ct < 4; ct++){
      const int col = cg*64 + ct*16 + lr;
      const bf16x8 bvh = __builtin_bit_cast(bf16x8, *(const ushort8_t*)&Bh[col*40 + lq*8]);
      const bf16x8 bvl = __builtin_bit_cast(bf16x8, *(const ushort8_t*)&Bl[col*40 + lq*8]);
      acc[ct] = __builtin_amdgcn_mfma_f32_16x16x32_bf16(avh, bvh, acc[ct], 0, 0, 0);
      acc[ct] = __builtin_amdgcn_mfma_f32_16x16x32_bf16(avh, bvl, acc[ct], 0, 0, 0);
      acc[ct] = __builtin_amdgcn_mfma_f32_16x16x32_bf16(avl, bvh, acc[ct], 0, 0, 0);
    }
    __syncthreads();
  }
  float pi[4] = {0.f,0.f,0.f,0.f}, pj[4] = {0.f,0.f,0.f,0.f};
  #pragma unroll
  for (int ct = 0; ct < 4; ct++){
    const int col = cg*64 + ct*16 + lr;
    const float fai = ai[col], faj = aj[col];
    #pragma unroll
    for (int q = 0; q < 4; q++){
      const float val = acc[ct][q];
      Wh[(size_t)(rbase + g*16 + lq*4 + q) * FOUT + col] = val;
      pi[q] = fmaf(val, fai, pi[q]);
      pj[q] = fmaf(val, faj, pj[q]);
    }
  }
  #pragma unroll
  for (int q = 0; q < 4; q++){
    #pragma unroll
    for (int m = 1; m < 16; m <<= 1){
      pi[q] += __shfl_xor(pi[q], m);
      pj[q] += __shfl_xor(pj[q], m);
    }
  }
  if (lr == 0){
    #pragma unroll
    for (int q = 0; q < 4; q++){
      spI[cg][g*16 + lq*4 + q] = pi[q];
      spJ[cg][g*16 + lq*4 + q] = pj[q];
    }
  }
  __syncthreads();
  if (t < 32){
    sI[rbase + t] = spI[0][t] + spI[1][t];
    sJ[rbase + t] = spJ[0][t] + spJ[1][t];
  }
}

// ---------------- K2: one-shot rank + scatter, 2 blocks/CU (r5-proven) ----------
// e1/e2 paired as float2 -> one 8B scatter store instead of two 4B.
__global__ __launch_bounds__(256) void k_rank_scatter(const float* __restrict__ sJ,
                                                      float* __restrict__ sortedS,
                                                      int* __restrict__ perm,
                                                      float2* __restrict__ e12g){
  const int b = blockIdx.x >> 6;        // 64 blocks per batch
  const int jc = blockIdx.x & 63;       // 32 j's per block
  __shared__ float v[NN];               // 8 KB
  __shared__ int partial[8][32];
  const int t = threadIdx.x;
  const float* sj = sJ + b * NN;
  #pragma unroll
  for (int u = 0; u < 2; u++)
    ((float4*)v)[t + u * 256] = ((const float4*)sj)[t + u * 256];
  const int jj = t & 31, qq = t >> 5;
  const int j = jc * 32 + jj;
  const float x = sj[j];
  __syncthreads();
  const int q0 = qq * 256;
  int r = 0;
  #pragma unroll 8
  for (int q4 = 0; q4 < 64; q4++){
    const int q = q0 + q4 * 4;
    float4 y = *(const float4*)&v[q];
    r += (y.x < x) || (y.x == x && (q + 0) < j);
    r += (y.y < x) || (y.y == x && (q + 1) < j);
    r += (y.z < x) || (y.z == x && (q + 2) < j);
    r += (y.w < x) || (y.w == x && (q + 3) < j);
  }
  partial[qq][jj] = r;
  __syncthreads();
  if (t < 32){
    int R = 0;
    #pragma unroll
    for (int q8 = 0; q8 < 8; q8++) R += partial[q8][t];
    const int myj = jc * 32 + t;
    const float xx = v[myj];
    sortedS[b * NN + R] = xx;
    perm[b * NN + R] = myj;
    e12g[b * NN + R] = make_float2(expf(xx), expf(0.01f * xx));
  }
}

// ---------------- K3: fused scans, 512-thread blocks (r5-proven structure) ------
// P12 now column-blocked [b][og(32)][row(NP1)][4]: each block's 4 cols are
// contiguous per row -> a 4-lane group's 16 unrolled stores fill 256 B
// contiguous; every 64B line is written by ONE wave (no cross-XCD partial-line
// RMW). abPre paired float2.
__global__ __launch_bounds__(512) void k_fuse(const float2* __restrict__ e12g,
                                              const float* __restrict__ Wh,
                                              const int* __restrict__ perm,
                                              float2* __restrict__ abPre,
                                              unsigned* __restrict__ P12){
  const int t = threadIdx.x;
  if (blockIdx.x < BATCH){
    // ---- scalar e-prefix sums, fully parallel (4 elems/thread, HS over 512) ----
    const int b = blockIdx.x;
    __shared__ float p1[512], p2[512];
    const float2* e12 = e12g + b * NN;
    float l1[4], l2[4];
    float s1 = 0.f, s2 = 0.f;
    #pragma unroll
    for (int q = 0; q < 4; q++){
      float2 v = e12[t * 4 + q];
      s1 += v.x; l1[q] = s1;
      s2 += v.y; l2[q] = s2;
    }
    p1[t] = s1; p2[t] = s2;
    __syncthreads();
    #pragma unroll
    for (int d = 1; d < 512; d <<= 1){
      const float u1 = (t >= d) ? p1[t - d] : 0.f;
      const float u2 = (t >= d) ? p2[t - d] : 0.f;
      __syncthreads();
      if (t >= d){ p1[t] += u1; p2[t] += u2; }
      __syncthreads();
    }
    const float b1 = p1[t] - s1, b2 = p2[t] - s2;   // exclusive offset
    float2* abP = abPre + b * NP1;
    #pragma unroll
    for (int q = 0; q < 4; q++)
      abP[1 + t * 4 + q] = make_float2(b1 + l1[q], b2 + l2[q]);
    if (t == 0) abP[0] = make_float2(0.f, 0.f);
    return;
  }
  // ---- fused column scan ----
  const int bc = blockIdx.x - BATCH;    // 0..255
  const int b = bc >> 5;                // 32 blocks per batch
  const int og = bc & 31;               // 4 output cols each
  const int ol = t & 3;
  const int o = og * 4 + ol;
  const int seg = t >> 2;               // 0..127
  const int r0 = seg * SLEN;
  __shared__ float p1[SEGS][4], p2[SEGS][4];
  const int*    pm  = perm + b * NN;
  const float2* e12 = e12g + b * NN;
  const float* whb = Wh + (size_t)b * NN * FOUT;
  float w[SLEN];
  float t1 = 0.f, t2 = 0.f;
  #pragma unroll
  for (int r = 0; r < SLEN; r++){       // full unroll: static w[] indices
    w[r] = whb[(size_t)pm[r0 + r] * FOUT + o];
    const float2 u = e12[r0 + r];
    t1 = fmaf(u.x, w[r], t1);
    t2 = fmaf(u.y, w[r], t2);
  }
  p1[seg][ol] = t1; p2[seg][ol] = t2;
  __syncthreads();
  #pragma unroll
  for (int d = 1; d < SEGS; d <<= 1){   // inclusive HS over 128 segs
    const float u1 = (seg >= d) ? p1[seg - d][ol] : 0.f;
    const float u2 = (seg >= d) ? p2[seg - d][ol] : 0.f;
    __syncthreads();
    if (seg >= d){ p1[seg][ol] += u1; p2[seg][ol] += u2; }
    __syncthreads();
  }
  float acc1 = p1[seg][ol] - t1;        // exclusive offset
  float acc2 = p2[seg][ol] - t2;
  unsigned* pp = P12 + ((size_t)(b * 32 + og) * NP1) * 4 + ol;
  if (seg == 0) pp[0] = 0u;
  #pragma unroll
  for (int r = 0; r < SLEN; r++){
    const float2 u = e12[r0 + r];
    acc1 = fmaf(u.x, w[r], acc1);
    acc2 = fmaf(u.y, w[r], acc2);
    pp[(size_t)(r0 + r + 1) * 4] = pack2(acc1, acc2);
  }
}

// ---------------- K4: per-row combine, 2 rows per block (r5-proven) -------------
__global__ __launch_bounds__(256) void k_out(const float* __restrict__ sI,
                                             const float* __restrict__ sortedS,
                                             const float2* __restrict__ abPre,
                                             const unsigned* __restrict__ P12,
                                             float* __restrict__ out){
  const int row = blockIdx.x * 2 + (threadIdx.x >> 7);
  const int b = row >> 11;
  const float s = sI[row];
  const float key = -s;
  const float* ss = sortedS + b * NN;
  int lo = 0, hi = NN;
  while (lo < hi){
    int mid = (lo + hi) >> 1;
    if (ss[mid] <= key) lo = mid + 1; else hi = mid;
  }
  const int k = lo;
  const float w1 = expf(s), w2 = expf(0.01f * s);
  const float2* abP = abPre + b * NP1;
  const float2 vT = abP[NN];
  const float2 vk = abP[k];
  const float inv = 1.0f / (w1 * (vT.x - vk.x) + w2 * vk.y);
  const int o = threadIdx.x & 127;
  const size_t pbase = (size_t)(b * 32 + (o >> 2)) * NP1;
  const unsigned uk = P12[(pbase + k)  * 4 + (o & 3)];
  const unsigned uT = P12[(pbase + NN) * 4 + (o & 3)];
  float num = w1 * (lo2f(uT) - lo2f(uk)) + w2 * hi2f(uk);
  out[(size_t)row * FOUT + o] = num * inv;
}

extern "C" void kernel_launch(void* const* d_in, const int* in_sizes, int n_in,
                              void* d_out, int out_size, void* d_ws, size_t ws_size,
                              hipStream_t stream){
  const float* h  = (const float*)d_in[0];
  const float* W  = (const float*)d_in[1];
  const float* ai = (const float*)d_in[2];
  const float* aj = (const float*)d_in[3];
  float* out = (float*)d_out;

  char* ws = (char*)d_ws;
  size_t off = 0;
  auto alloc = [&](size_t bytes) -> void* {
    void* p = ws + off;
    off += (bytes + 255) & ~(size_t)255;
    return p;
  };
  float*          Wh   = (float*)   alloc((size_t)ROWS * FOUT * 4);        // 8 MB
  float*          sI   = (float*)   alloc((size_t)ROWS * 4);
  float*          sJ   = (float*)   alloc((size_t)ROWS * 4);
  float*          sortedS = (float*)alloc((size_t)BATCH * NN * 4);
  int*            perm = (int*)     alloc((size_t)BATCH * NN * 4);
  float2*         e12  = (float2*)  alloc((size_t)BATCH * NN * 8);
  float2*         abPre= (float2*)  alloc((size_t)BATCH * NP1 * 8);
  unsigned*       P12  = (unsigned*)alloc((size_t)BATCH * 32 * NP1 * 4 * 4); // 8.4 MB
  unsigned short* Wth  = (unsigned short*)alloc((size_t)FOUT * FIN * 2);   // 64 KB
  unsigned short* Wtl  = (unsigned short*)alloc((size_t)FOUT * FIN * 2);   // 64 KB

  k_wsplit      <<<32, 256, 0, stream>>>(W, Wth, Wtl);
  k_gemm        <<<ROWS / 32, 256, 0, stream>>>(h, Wth, Wtl, ai, aj, Wh, sI, sJ);
  k_rank_scatter<<<BATCH * 64, 256, 0, stream>>>(sJ, sortedS, perm, e12);
  k_fuse        <<<BATCH + BATCH * 32, 512, 0, stream>>>(e12, Wh, perm, abPre, P12);
  k_out         <<<ROWS / 2, 256, 0, stream>>>(sI, sortedS, abPre, P12, out);
}

// Round 7
// 116.304 us; speedup vs baseline: 2.6066x; 1.0877x over previous
//
#include <hip/hip_runtime.h>
#include <hip/hip_bf16.h>

#define BATCH 8
#define NN 2048
#define FIN 256
#define FOUT 128
#define ROWS (BATCH*NN)
#define NP1 (NN+1)
#define SEGS 128         // row segments per batch in k_fuseout
#define SLEN (NN/SEGS)   // 16 rows per segment

typedef __attribute__((ext_vector_type(8))) __bf16 bf16x8;
typedef __attribute__((ext_vector_type(4))) float f32x4;
typedef __attribute__((ext_vector_type(8))) unsigned short ushort8_t;

__device__ __forceinline__ unsigned pack2(float a, float b){
  __hip_bfloat16 x = __float2bfloat16(a), y = __float2bfloat16(b);
  unsigned short ux = *(unsigned short*)&x, uy = *(unsigned short*)&y;
  return ((unsigned)uy << 16) | (unsigned)ux;
}
__device__ __forceinline__ float lo2f(unsigned u){ union{unsigned v;float f;}c; c.v = u << 16; return c.f; }
__device__ __forceinline__ float hi2f(unsigned u){ union{unsigned v;float f;}c; c.v = u & 0xffff0000u; return c.f; }

// split x into bf16 hi + bf16 lo (x ≈ hi + lo, error ~2^-17 relative)
__device__ __forceinline__ void bsplit(float x, unsigned short& hu, unsigned short& lu){
  __hip_bfloat16 hb = __float2bfloat16(x);
  hu = *(unsigned short*)&hb;
  union{unsigned u; float f;} hf; hf.u = (unsigned)hu << 16;
  __hip_bfloat16 lb = __float2bfloat16(x - hf.f);
  lu = *(unsigned short*)&lb;
}

// ---------------- K0: split W -> transposed bf16 hi/lo [col][k] (r4-proven) ----
__global__ __launch_bounds__(256) void k_wsplit(const float* __restrict__ W,
                                                unsigned short* __restrict__ Wth,
                                                unsigned short* __restrict__ Wtl){
  const int gid = blockIdx.x * 256 + threadIdx.x;   // 0..8191
  const int k = gid >> 5, c4 = (gid & 31) * 4;
  float4 v = *(const float4*)&W[(size_t)k * FOUT + c4];
  float xs[4] = {v.x, v.y, v.z, v.w};
  #pragma unroll
  for (int i = 0; i < 4; i++){
    unsigned short hu, lu;
    bsplit(xs[i], hu, lu);
    Wth[(size_t)(c4 + i) * FIN + k] = hu;
    Wtl[(size_t)(c4 + i) * FIN + k] = lu;
  }
}

// ---------------- K1: MFMA split-bf16 Wh = h @ W + fused s_i/s_j (r4-proven) ----
__global__ __launch_bounds__(256) void k_gemm(const float* __restrict__ h,
                                              const unsigned short* __restrict__ Wth,
                                              const unsigned short* __restrict__ Wtl,
                                              const float* __restrict__ ai,
                                              const float* __restrict__ aj,
                                              float* __restrict__ Wh,
                                              float* __restrict__ sI,
                                              float* __restrict__ sJ){
  __shared__ unsigned short Ah[32*40], Al[32*40];     // [row][k] pad 40 ushort (80 B)
  __shared__ unsigned short Bh[128*40], Bl[128*40];   // [col][k] pad 40
  __shared__ float spI[2][32], spJ[2][32];
  const int t = threadIdx.x;
  const int rbase = blockIdx.x * 32;
  const int w = t >> 6, l = t & 63;
  const int g = w & 1, cg = w >> 1;       // row-half, col-group(64)
  const int lr = l & 15, lq = l >> 4;     // M/N low index, k-quarter
  const int sar = t >> 3, sak = (t & 7) * 4;   // A staging: row, k-off (4 floats)
  const int sbc = t >> 1, sbh = (t & 1) * 16;  // B staging: col, k-half

  f32x4 acc[4];
  #pragma unroll
  for (int ct = 0; ct < 4; ct++) acc[ct] = (f32x4){0.f, 0.f, 0.f, 0.f};

  for (int k0 = 0; k0 < FIN; k0 += 32){
    {
      float4 hv = *(const float4*)&h[(size_t)(rbase + sar) * FIN + k0 + sak];
      float xs[4] = {hv.x, hv.y, hv.z, hv.w};
      ushort4 hh, ll;
      unsigned short hu, lu;
      bsplit(xs[0], hu, lu); hh.x = hu; ll.x = lu;
      bsplit(xs[1], hu, lu); hh.y = hu; ll.y = lu;
      bsplit(xs[2], hu, lu); hh.z = hu; ll.z = lu;
      bsplit(xs[3], hu, lu); hh.w = hu; ll.w = lu;
      *(ushort4*)&Ah[sar * 40 + sak] = hh;
      *(ushort4*)&Al[sar * 40 + sak] = ll;
    }
    {
      const size_t gb = (size_t)sbc * FIN + k0 + sbh;
      ushort8_t b0 = *(const ushort8_t*)&Wth[gb];
      ushort8_t b1 = *(const ushort8_t*)&Wth[gb + 8];
      ushort8_t c0 = *(const ushort8_t*)&Wtl[gb];
      ushort8_t c1 = *(const ushort8_t*)&Wtl[gb + 8];
      *(ushort8_t*)&Bh[sbc * 40 + sbh]     = b0;
      *(ushort8_t*)&Bh[sbc * 40 + sbh + 8] = b1;
      *(ushort8_t*)&Bl[sbc * 40 + sbh]     = c0;
      *(ushort8_t*)&Bl[sbc * 40 + sbh + 8] = c1;
    }
    __syncthreads();
    const bf16x8 avh = __builtin_bit_cast(bf16x8, *(const ushort8_t*)&Ah[(g*16 + lr)*40 + lq*8]);
    const bf16x8 avl = __builtin_bit_cast(bf16x8, *(const ushort8_t*)&Al[(g*16 + lr)*40 + lq*8]);
    #pragma unroll
    for (int ct = 0; ct < 4; ct++){
      const int col = cg*64 + ct*16 + lr;
      const bf16x8 bvh = __builtin_bit_cast(bf16x8, *(const ushort8_t*)&Bh[col*40 + lq*8]);
      const bf16x8 bvl = __builtin_bit_cast(bf16x8, *(const ushort8_t*)&Bl[col*40 + lq*8]);
      acc[ct] = __builtin_amdgcn_mfma_f32_16x16x32_bf16(avh, bvh, acc[ct], 0, 0, 0);
      acc[ct] = __builtin_amdgcn_mfma_f32_16x16x32_bf16(avh, bvl, acc[ct], 0, 0, 0);
      acc[ct] = __builtin_amdgcn_mfma_f32_16x16x32_bf16(avl, bvh, acc[ct], 0, 0, 0);
    }
    __syncthreads();
  }
  float pi[4] = {0.f,0.f,0.f,0.f}, pj[4] = {0.f,0.f,0.f,0.f};
  #pragma unroll
  for (int ct = 0; ct < 4; ct++){
    const int col = cg*64 + ct*16 + lr;
    const float fai = ai[col], faj = aj[col];
    #pragma unroll
    for (int q = 0; q < 4; q++){
      const float val = acc[ct][q];
      Wh[(size_t)(rbase + g*16 + lq*4 + q) * FOUT + col] = val;
      pi[q] = fmaf(val, fai, pi[q]);
      pj[q] = fmaf(val, faj, pj[q]);
    }
  }
  #pragma unroll
  for (int q = 0; q < 4; q++){
    #pragma unroll
    for (int m = 1; m < 16; m <<= 1){
      pi[q] += __shfl_xor(pi[q], m);
      pj[q] += __shfl_xor(pj[q], m);
    }
  }
  if (lr == 0){
    #pragma unroll
    for (int q = 0; q < 4; q++){
      spI[cg][g*16 + lq*4 + q] = pi[q];
      spJ[cg][g*16 + lq*4 + q] = pj[q];
    }
  }
  __syncthreads();
  if (t < 32){
    sI[rbase + t] = spI[0][t] + spI[1][t];
    sJ[rbase + t] = spJ[0][t] + spJ[1][t];
  }
}

// ---------------- K2: one-shot rank + scatter, 2 blocks/CU (r5-proven) ----------
__global__ __launch_bounds__(256) void k_rank_scatter(const float* __restrict__ sJ,
                                                      float* __restrict__ sortedS,
                                                      int* __restrict__ perm,
                                                      float2* __restrict__ e12g){
  const int b = blockIdx.x >> 6;        // 64 blocks per batch
  const int jc = blockIdx.x & 63;       // 32 j's per block
  __shared__ float v[NN];               // 8 KB
  __shared__ int partial[8][32];
  const int t = threadIdx.x;
  const float* sj = sJ + b * NN;
  #pragma unroll
  for (int u = 0; u < 2; u++)
    ((float4*)v)[t + u * 256] = ((const float4*)sj)[t + u * 256];
  const int jj = t & 31, qq = t >> 5;
  const int j = jc * 32 + jj;
  const float x = sj[j];
  __syncthreads();
  const int q0 = qq * 256;
  int r = 0;
  #pragma unroll 8
  for (int q4 = 0; q4 < 64; q4++){
    const int q = q0 + q4 * 4;
    float4 y = *(const float4*)&v[q];
    r += (y.x < x) || (y.x == x && (q + 0) < j);
    r += (y.y < x) || (y.y == x && (q + 1) < j);
    r += (y.z < x) || (y.z == x && (q + 2) < j);
    r += (y.w < x) || (y.w == x && (q + 3) < j);
  }
  partial[qq][jj] = r;
  __syncthreads();
  if (t < 32){
    int R = 0;
    #pragma unroll
    for (int q8 = 0; q8 < 8; q8++) R += partial[q8][t];
    const int myj = jc * 32 + t;
    const float xx = v[myj];
    sortedS[b * NN + R] = xx;
    perm[b * NN + R] = myj;
    e12g[b * NN + R] = make_float2(expf(xx), expf(0.01f * xx));
  }
}

// ---------------- K3: fully-fused column scan + epilogue ----------------
// Block (b, og) owns 4 output columns. Gather w into regs -> seg totals
// (4 cols + scalar) -> HS scan over 128 segs -> walk writes packed P and
// a/b scalar prefix to LDS -> barrier -> 16 rows/thread: LDS binary search,
// combine, store out. No global P12/abPre, no k_out dispatch.
__global__ __launch_bounds__(512) void k_fuseout(const float* __restrict__ sortedS,
                                                 const float* __restrict__ sI,
                                                 const float2* __restrict__ e12g,
                                                 const float* __restrict__ Wh,
                                                 const int* __restrict__ perm,
                                                 float* __restrict__ out){
  __shared__ float    ssL[NN];          // 8192 B  sorted s (for searches)
  __shared__ float2   abL[NP1];         // 16392 B scalar e1/e2 prefix
  __shared__ unsigned PL[NP1][4];       // 32784 B packed P, own 4 cols
  __shared__ float p1[SEGS][4], p2[SEGS][4];   // 4096 B seg totals (w-weighted)
  __shared__ float p1s[SEGS], p2s[SEGS];       // 1024 B seg totals (scalar)
  const int bc = blockIdx.x;            // 0..255
  const int b = bc >> 5;                // 32 blocks per batch
  const int og = bc & 31;               // 4 output cols each
  const int t = threadIdx.x;
  const int ol = t & 3;
  const int o = og * 4 + ol;
  const int seg = t >> 2;               // 0..127
  const int r0 = seg * SLEN;

  // stage sortedS for the search phase (consumed after later barriers)
  const float* ssg = sortedS + b * NN;
  #pragma unroll
  for (int u = 0; u < 4; u++) ssL[t + u * 512] = ssg[t + u * 512];

  const int*    pm  = perm + b * NN;
  const float2* e12 = e12g + b * NN;
  const float*  whb = Wh + (size_t)b * NN * FOUT;
  float w[SLEN], ex[SLEN], ey[SLEN];
  float t1 = 0.f, t2 = 0.f, s1 = 0.f, s2 = 0.f;
  #pragma unroll
  for (int r = 0; r < SLEN; r++){       // full unroll: static reg indices
    w[r] = whb[(size_t)pm[r0 + r] * FOUT + o];
    const float2 u = e12[r0 + r];
    ex[r] = u.x; ey[r] = u.y;
    t1 = fmaf(u.x, w[r], t1);
    t2 = fmaf(u.y, w[r], t2);
    s1 += u.x; s2 += u.y;
  }
  p1[seg][ol] = t1; p2[seg][ol] = t2;
  if (ol == 0){ p1s[seg] = s1; p2s[seg] = s2; }
  __syncthreads();
  #pragma unroll
  for (int d = 1; d < SEGS; d <<= 1){   // inclusive HS over 128 segs
    const float u1 = (seg >= d) ? p1[seg - d][ol] : 0.f;
    const float u2 = (seg >= d) ? p2[seg - d][ol] : 0.f;
    const float v1 = (ol == 0 && seg >= d) ? p1s[seg - d] : 0.f;
    const float v2 = (ol == 0 && seg >= d) ? p2s[seg - d] : 0.f;
    __syncthreads();
    if (seg >= d){
      p1[seg][ol] += u1; p2[seg][ol] += u2;
      if (ol == 0){ p1s[seg] += v1; p2s[seg] += v2; }
    }
    __syncthreads();
  }
  float acc1 = p1[seg][ol] - t1;        // exclusive offsets
  float acc2 = p2[seg][ol] - t2;
  if (seg == 0){
    PL[0][ol] = 0u;
    if (ol == 0) abL[0] = make_float2(0.f, 0.f);
  }
  {
    float offs1 = 0.f, offs2 = 0.f;
    if (ol == 0){ offs1 = p1s[seg] - s1; offs2 = p2s[seg] - s2; }
    float run1 = 0.f, run2 = 0.f;
    #pragma unroll
    for (int r = 0; r < SLEN; r++){
      acc1 = fmaf(ex[r], w[r], acc1);
      acc2 = fmaf(ey[r], w[r], acc2);
      PL[r0 + r + 1][ol] = pack2(acc1, acc2);
      if (ol == 0){
        run1 += ex[r]; run2 += ey[r];
        abL[r0 + r + 1] = make_float2(offs1 + run1, offs2 + run2);
      }
    }
  }
  __syncthreads();
  // ---- epilogue: 16 rows per thread, breadth-first LDS binary searches ----
  const int tg = t >> 2;                // 0..127; rows tg + u*128
  float sv[16];
  #pragma unroll
  for (int u = 0; u < 16; u++) sv[u] = sI[b * NN + tg + u * 128];
  int lo[16], hi[16];
  #pragma unroll
  for (int u = 0; u < 16; u++){ lo[u] = 0; hi[u] = NN; }
  #pragma unroll
  for (int step = 0; step < 11; step++){    // fixed 11 iters for N=2048
    float mv[16]; int mid[16];
    #pragma unroll
    for (int u = 0; u < 16; u++){
      mid[u] = (lo[u] + hi[u]) >> 1;
      mv[u] = ssL[mid[u]];
    }
    #pragma unroll
    for (int u = 0; u < 16; u++){
      if (mv[u] <= -sv[u]) lo[u] = mid[u] + 1; else hi[u] = mid[u];
    }
  }
  const float2 vT = abL[NN];
  const unsigned uTp = PL[NN][ol];
  #pragma unroll
  for (int u = 0; u < 16; u++){
    const int row = tg + u * 128;
    const int k = lo[u];
    const float s = sv[u];
    const float w1 = expf(s), w2 = expf(0.01f * s);
    const float2 vk = abL[k];
    const float inv = 1.0f / (w1 * (vT.x - vk.x) + w2 * vk.y);
    const unsigned uk = PL[k][ol];
    const float num = w1 * (lo2f(uTp) - lo2f(uk)) + w2 * hi2f(uk);
    out[(size_t)(b * NN + row) * FOUT + o] = num * inv;
  }
}

extern "C" void kernel_launch(void* const* d_in, const int* in_sizes, int n_in,
                              void* d_out, int out_size, void* d_ws, size_t ws_size,
                              hipStream_t stream){
  const float* h  = (const float*)d_in[0];
  const float* W  = (const float*)d_in[1];
  const float* ai = (const float*)d_in[2];
  const float* aj = (const float*)d_in[3];
  float* out = (float*)d_out;

  char* ws = (char*)d_ws;
  size_t off = 0;
  auto alloc = [&](size_t bytes) -> void* {
    void* p = ws + off;
    off += (bytes + 255) & ~(size_t)255;
    return p;
  };
  float*          Wh   = (float*)   alloc((size_t)ROWS * FOUT * 4);        // 8 MB
  float*          sI   = (float*)   alloc((size_t)ROWS * 4);
  float*          sJ   = (float*)   alloc((size_t)ROWS * 4);
  float*          sortedS = (float*)alloc((size_t)BATCH * NN * 4);
  int*            perm = (int*)     alloc((size_t)BATCH * NN * 4);
  float2*         e12  = (float2*)  alloc((size_t)BATCH * NN * 8);
  unsigned short* Wth  = (unsigned short*)alloc((size_t)FOUT * FIN * 2);   // 64 KB
  unsigned short* Wtl  = (unsigned short*)alloc((size_t)FOUT * FIN * 2);   // 64 KB

  k_wsplit      <<<32, 256, 0, stream>>>(W, Wth, Wtl);
  k_gemm        <<<ROWS / 32, 256, 0, stream>>>(h, Wth, Wtl, ai, aj, Wh, sI, sJ);
  k_rank_scatter<<<BATCH * 64, 256, 0, stream>>>(sJ, sortedS, perm, e12);
  k_fuseout     <<<BATCH * 32, 512, 0, stream>>>(sortedS, sI, e12, Wh, perm, out);
}

// Round 8
// 109.751 us; speedup vs baseline: 2.7622x; 1.0597x over previous
//
#include <hip/hip_runtime.h>
#include <hip/hip_bf16.h>

#define BATCH 8
#define NN 2048
#define FIN 256
#define FOUT 128
#define ROWS (BATCH*NN)
#define NP1 (NN+1)
#define SEGS 128         // row segments per batch in k_fuseout
#define SLEN (NN/SEGS)   // 16 rows per segment

typedef __attribute__((ext_vector_type(8))) __bf16 bf16x8;
typedef __attribute__((ext_vector_type(4))) float f32x4;
typedef __attribute__((ext_vector_type(8))) unsigned short ushort8_t;

__device__ __forceinline__ unsigned pack2(float a, float b){
  __hip_bfloat16 x = __float2bfloat16(a), y = __float2bfloat16(b);
  unsigned short ux = *(unsigned short*)&x, uy = *(unsigned short*)&y;
  return ((unsigned)uy << 16) | (unsigned)ux;
}
__device__ __forceinline__ float lo2f(unsigned u){ union{unsigned v;float f;}c; c.v = u << 16; return c.f; }
__device__ __forceinline__ float hi2f(unsigned u){ union{unsigned v;float f;}c; c.v = u & 0xffff0000u; return c.f; }

// split x into bf16 hi + bf16 lo (x ≈ hi + lo, error ~2^-17 relative)
__device__ __forceinline__ void bsplit(float x, unsigned short& hu, unsigned short& lu){
  __hip_bfloat16 hb = __float2bfloat16(x);
  hu = *(unsigned short*)&hb;
  union{unsigned u; float f;} hf; hf.u = (unsigned)hu << 16;
  __hip_bfloat16 lb = __float2bfloat16(x - hf.f);
  lu = *(unsigned short*)&lb;
}

// ---------------- K0: split W -> transposed bf16 hi/lo [col][k] (r4-proven) ----
__global__ __launch_bounds__(256) void k_wsplit(const float* __restrict__ W,
                                                unsigned short* __restrict__ Wth,
                                                unsigned short* __restrict__ Wtl){
  const int gid = blockIdx.x * 256 + threadIdx.x;   // 0..8191
  const int k = gid >> 5, c4 = (gid & 31) * 4;
  float4 v = *(const float4*)&W[(size_t)k * FOUT + c4];
  float xs[4] = {v.x, v.y, v.z, v.w};
  #pragma unroll
  for (int i = 0; i < 4; i++){
    unsigned short hu, lu;
    bsplit(xs[i], hu, lu);
    Wth[(size_t)(c4 + i) * FIN + k] = hu;
    Wtl[(size_t)(c4 + i) * FIN + k] = lu;
  }
}

// ---------------- K1: MFMA split-bf16 Wh = h @ W + fused s_i/s_j ----------------
// Wh stored COLUMN-BLOCKED [b][og(32)][row(NN)][4]: k_fuseout block (b,og) then
// owns a private contiguous 32 KB slice (L1-sized) -> no cross-block line waste.
__global__ __launch_bounds__(256) void k_gemm(const float* __restrict__ h,
                                              const unsigned short* __restrict__ Wth,
                                              const unsigned short* __restrict__ Wtl,
                                              const float* __restrict__ ai,
                                              const float* __restrict__ aj,
                                              float* __restrict__ Wh,
                                              float* __restrict__ sI,
                                              float* __restrict__ sJ){
  __shared__ unsigned short Ah[32*40], Al[32*40];     // [row][k] pad 40 ushort (80 B)
  __shared__ unsigned short Bh[128*40], Bl[128*40];   // [col][k] pad 40
  __shared__ float spI[2][32], spJ[2][32];
  const int t = threadIdx.x;
  const int rbase = blockIdx.x * 32;
  const int b = rbase >> 11;
  const int brow0 = rbase & (NN - 1);
  const int w = t >> 6, l = t & 63;
  const int g = w & 1, cg = w >> 1;       // row-half, col-group(64)
  const int lr = l & 15, lq = l >> 4;     // M/N low index, k-quarter
  const int sar = t >> 3, sak = (t & 7) * 4;   // A staging: row, k-off (4 floats)
  const int sbc = t >> 1, sbh = (t & 1) * 16;  // B staging: col, k-half

  f32x4 acc[4];
  #pragma unroll
  for (int ct = 0; ct < 4; ct++) acc[ct] = (f32x4){0.f, 0.f, 0.f, 0.f};

  for (int k0 = 0; k0 < FIN; k0 += 32){
    {
      float4 hv = *(const float4*)&h[(size_t)(rbase + sar) * FIN + k0 + sak];
      float xs[4] = {hv.x, hv.y, hv.z, hv.w};
      ushort4 hh, ll;
      unsigned short hu, lu;
      bsplit(xs[0], hu, lu); hh.x = hu; ll.x = lu;
      bsplit(xs[1], hu, lu); hh.y = hu; ll.y = lu;
      bsplit(xs[2], hu, lu); hh.z = hu; ll.z = lu;
      bsplit(xs[3], hu, lu); hh.w = hu; ll.w = lu;
      *(ushort4*)&Ah[sar * 40 + sak] = hh;
      *(ushort4*)&Al[sar * 40 + sak] = ll;
    }
    {
      const size_t gb = (size_t)sbc * FIN + k0 + sbh;
      ushort8_t b0 = *(const ushort8_t*)&Wth[gb];
      ushort8_t b1 = *(const ushort8_t*)&Wth[gb + 8];
      ushort8_t c0 = *(const ushort8_t*)&Wtl[gb];
      ushort8_t c1 = *(const ushort8_t*)&Wtl[gb + 8];
      *(ushort8_t*)&Bh[sbc * 40 + sbh]     = b0;
      *(ushort8_t*)&Bh[sbc * 40 + sbh + 8] = b1;
      *(ushort8_t*)&Bl[sbc * 40 + sbh]     = c0;
      *(ushort8_t*)&Bl[sbc * 40 + sbh + 8] = c1;
    }
    __syncthreads();
    const bf16x8 avh = __builtin_bit_cast(bf16x8, *(const ushort8_t*)&Ah[(g*16 + lr)*40 + lq*8]);
    const bf16x8 avl = __builtin_bit_cast(bf16x8, *(const ushort8_t*)&Al[(g*16 + lr)*40 + lq*8]);
    #pragma unroll
    for (int ct = 0; ct < 4; ct++){
      const int col = cg*64 + ct*16 + lr;
      const bf16x8 bvh = __builtin_bit_cast(bf16x8, *(const ushort8_t*)&Bh[col*40 + lq*8]);
      const bf16x8 bvl = __builtin_bit_cast(bf16x8, *(const ushort8_t*)&Bl[col*40 + lq*8]);
      acc[ct] = __builtin_amdgcn_mfma_f32_16x16x32_bf16(avh, bvh, acc[ct], 0, 0, 0);
      acc[ct] = __builtin_amdgcn_mfma_f32_16x16x32_bf16(avh, bvl, acc[ct], 0, 0, 0);
      acc[ct] = __builtin_amdgcn_mfma_f32_16x16x32_bf16(avl, bvh, acc[ct], 0, 0, 0);
    }
    __syncthreads();
  }
  float pi[4] = {0.f,0.f,0.f,0.f}, pj[4] = {0.f,0.f,0.f,0.f};
  #pragma unroll
  for (int ct = 0; ct < 4; ct++){
    const int col = cg*64 + ct*16 + lr;
    const int og = col >> 2, ol2 = col & 3;
    const float fai = ai[col], faj = aj[col];
    const size_t obase = ((size_t)(b * 32 + og) * NN + brow0 + g*16 + lq*4) * 4 + ol2;
    #pragma unroll
    for (int q = 0; q < 4; q++){
      const float val = acc[ct][q];
      Wh[obase + (size_t)q * 4] = val;
      pi[q] = fmaf(val, fai, pi[q]);
      pj[q] = fmaf(val, faj, pj[q]);
    }
  }
  #pragma unroll
  for (int q = 0; q < 4; q++){
    #pragma unroll
    for (int m = 1; m < 16; m <<= 1){
      pi[q] += __shfl_xor(pi[q], m);
      pj[q] += __shfl_xor(pj[q], m);
    }
  }
  if (lr == 0){
    #pragma unroll
    for (int q = 0; q < 4; q++){
      spI[cg][g*16 + lq*4 + q] = pi[q];
      spJ[cg][g*16 + lq*4 + q] = pj[q];
    }
  }
  __syncthreads();
  if (t < 32){
    sI[rbase + t] = spI[0][t] + spI[1][t];
    sJ[rbase + t] = spJ[0][t] + spJ[1][t];
  }
}

// ---------------- K2: one-shot rank + scatter, 2 blocks/CU (r5-proven) ----------
__global__ __launch_bounds__(256) void k_rank_scatter(const float* __restrict__ sJ,
                                                      float* __restrict__ sortedS,
                                                      int* __restrict__ perm,
                                                      float2* __restrict__ e12g){
  const int b = blockIdx.x >> 6;        // 64 blocks per batch
  const int jc = blockIdx.x & 63;       // 32 j's per block
  __shared__ float v[NN];               // 8 KB
  __shared__ int partial[8][32];
  const int t = threadIdx.x;
  const float* sj = sJ + b * NN;
  #pragma unroll
  for (int u = 0; u < 2; u++)
    ((float4*)v)[t + u * 256] = ((const float4*)sj)[t + u * 256];
  const int jj = t & 31, qq = t >> 5;
  const int j = jc * 32 + jj;
  const float x = sj[j];
  __syncthreads();
  const int q0 = qq * 256;
  int r = 0;
  #pragma unroll 8
  for (int q4 = 0; q4 < 64; q4++){
    const int q = q0 + q4 * 4;
    float4 y = *(const float4*)&v[q];
    r += (y.x < x) || (y.x == x && (q + 0) < j);
    r += (y.y < x) || (y.y == x && (q + 1) < j);
    r += (y.z < x) || (y.z == x && (q + 2) < j);
    r += (y.w < x) || (y.w == x && (q + 3) < j);
  }
  partial[qq][jj] = r;
  __syncthreads();
  if (t < 32){
    int R = 0;
    #pragma unroll
    for (int q8 = 0; q8 < 8; q8++) R += partial[q8][t];
    const int myj = jc * 32 + t;
    const float xx = v[myj];
    sortedS[b * NN + R] = xx;
    perm[b * NN + R] = myj;
    e12g[b * NN + R] = make_float2(expf(xx), expf(0.01f * xx));
  }
}

// ---------------- K3: fully-fused column scan + epilogue ----------------
// Block (b, og) owns 4 output columns; Wh slice is private/contiguous (32 KB).
// Seg-total scan = wave-level shfl_up (16 segs/wave) + 1-barrier cross-wave
// fixup (was 14-barrier Hillis-Steele). Scalar e-sums ride the same shuffles.
__global__ __launch_bounds__(512) void k_fuseout(const float* __restrict__ sortedS,
                                                 const float* __restrict__ sI,
                                                 const float2* __restrict__ e12g,
                                                 const float* __restrict__ Wh,
                                                 const int* __restrict__ perm,
                                                 float* __restrict__ out){
  __shared__ float    ssL[NN];          // 8192 B  sorted s (for searches)
  __shared__ float2   abL[NP1];         // 16392 B scalar e1/e2 prefix
  __shared__ unsigned PL[NP1][4];       // 32784 B packed P, own 4 cols
  __shared__ float wtP1[8][4], wtP2[8][4], wtS1[8], wtS2[8];  // wave totals
  const int bc = blockIdx.x;            // 0..255
  const int b = bc >> 5;                // 32 blocks per batch
  const int og = bc & 31;               // 4 output cols each
  const int t = threadIdx.x;
  const int ol = t & 3;
  const int seg = t >> 2;               // 0..127
  const int r0 = seg * SLEN;
  const int wv = t >> 6, wl = t & 63;   // wave id / lane (seg = wv*16 + (wl>>2))

  // stage sortedS for the search phase (consumed after later barriers)
  const float* ssg = sortedS + b * NN;
  #pragma unroll
  for (int u = 0; u < 4; u++) ssL[t + u * 512] = ssg[t + u * 512];

  const int*    pm  = perm + b * NN;
  const float2* e12 = e12g + b * NN;
  const float*  whb = Wh + (size_t)(b * 32 + og) * NN * 4;   // private 32 KB slice
  float w[SLEN], ex[SLEN], ey[SLEN];
  float t1 = 0.f, t2 = 0.f, s1 = 0.f, s2 = 0.f;
  #pragma unroll
  for (int r = 0; r < SLEN; r++){       // full unroll: static reg indices
    w[r] = whb[(size_t)pm[r0 + r] * 4 + ol];
    const float2 u = e12[r0 + r];
    ex[r] = u.x; ey[r] = u.y;
    t1 = fmaf(u.x, w[r], t1);
    t2 = fmaf(u.y, w[r], t2);
    s1 += u.x; s2 += u.y;
  }
  // ---- wave-level inclusive scan over segs (p1,p2 all lanes; s1,s2 valid @ol==0) ----
  float c1 = t1, c2 = t2, cs1 = s1, cs2 = s2;
  #pragma unroll
  for (int d = 1; d < 16; d <<= 1){
    const float u1 = __shfl_up(c1, d * 4);
    const float u2 = __shfl_up(c2, d * 4);
    const float u3 = __shfl_up(cs1, d * 4);
    const float u4 = __shfl_up(cs2, d * 4);
    if ((wl >> 2) >= d){ c1 += u1; c2 += u2; cs1 += u3; cs2 += u4; }
  }
  if ((wl >> 2) == 15){                 // last seg of wave: wave totals
    wtP1[wv][ol] = c1; wtP2[wv][ol] = c2;
    if (ol == 0){ wtS1[wv] = cs1; wtS2[wv] = cs2; }
  }
  __syncthreads();
  for (int ww = 0; ww < wv; ww++){      // cross-wave exclusive fixup (wave-uniform)
    c1 += wtP1[ww][ol]; c2 += wtP2[ww][ol];
    cs1 += wtS1[ww];    cs2 += wtS2[ww];
  }
  float acc1 = c1 - t1;                 // exclusive offsets
  float acc2 = c2 - t2;
  if (seg == 0){
    PL[0][ol] = 0u;
    if (ol == 0) abL[0] = make_float2(0.f, 0.f);
  }
  {
    float offs1 = 0.f, offs2 = 0.f;
    if (ol == 0){ offs1 = cs1 - s1; offs2 = cs2 - s2; }
    float run1 = 0.f, run2 = 0.f;
    #pragma unroll
    for (int r = 0; r < SLEN; r++){
      acc1 = fmaf(ex[r], w[r], acc1);
      acc2 = fmaf(ey[r], w[r], acc2);
      PL[r0 + r + 1][ol] = pack2(acc1, acc2);
      if (ol == 0){
        run1 += ex[r]; run2 += ey[r];
        abL[r0 + r + 1] = make_float2(offs1 + run1, offs2 + run2);
      }
    }
  }
  __syncthreads();
  // ---- epilogue: 16 rows per thread, breadth-first LDS binary searches ----
  const int tg = t >> 2;                // 0..127; rows tg + u*128
  float sv[16];
  #pragma unroll
  for (int u = 0; u < 16; u++) sv[u] = sI[b * NN + tg + u * 128];
  int lo[16], hi[16];
  #pragma unroll
  for (int u = 0; u < 16; u++){ lo[u] = 0; hi[u] = NN; }
  #pragma unroll
  for (int step = 0; step < 11; step++){    // fixed 11 iters for N=2048
    float mv[16]; int mid[16];
    #pragma unroll
    for (int u = 0; u < 16; u++){
      mid[u] = (lo[u] + hi[u]) >> 1;
      mv[u] = ssL[mid[u]];
    }
    #pragma unroll
    for (int u = 0; u < 16; u++){
      if (mv[u] <= -sv[u]) lo[u] = mid[u] + 1; else hi[u] = mid[u];
    }
  }
  const float2 vT = abL[NN];
  const unsigned uTp = PL[NN][ol];
  #pragma unroll
  for (int u = 0; u < 16; u++){
    const int row = tg + u * 128;
    const int k = lo[u];
    const float s = sv[u];
    const float w1 = expf(s), w2 = expf(0.01f * s);
    const float2 vk = abL[k];
    const float inv = 1.0f / (w1 * (vT.x - vk.x) + w2 * vk.y);
    const unsigned uk = PL[k][ol];
    const float num = w1 * (lo2f(uTp) - lo2f(uk)) + w2 * hi2f(uk);
    out[(size_t)(b * NN + row) * FOUT + og * 4 + ol] = num * inv;
  }
}

extern "C" void kernel_launch(void* const* d_in, const int* in_sizes, int n_in,
                              void* d_out, int out_size, void* d_ws, size_t ws_size,
                              hipStream_t stream){
  const float* h  = (const float*)d_in[0];
  const float* W  = (const float*)d_in[1];
  const float* ai = (const float*)d_in[2];
  const float* aj = (const float*)d_in[3];
  float* out = (float*)d_out;

  char* ws = (char*)d_ws;
  size_t off = 0;
  auto alloc = [&](size_t bytes) -> void* {
    void* p = ws + off;
    off += (bytes + 255) & ~(size_t)255;
    return p;
  };
  float*          Wh   = (float*)   alloc((size_t)ROWS * FOUT * 4);        // 8 MB (blocked)
  float*          sI   = (float*)   alloc((size_t)ROWS * 4);
  float*          sJ   = (float*)   alloc((size_t)ROWS * 4);
  float*          sortedS = (float*)alloc((size_t)BATCH * NN * 4);
  int*            perm = (int*)     alloc((size_t)BATCH * NN * 4);
  float2*         e12  = (float2*)  alloc((size_t)BATCH * NN * 8);
  unsigned short* Wth  = (unsigned short*)alloc((size_t)FOUT * FIN * 2);   // 64 KB
  unsigned short* Wtl  = (unsigned short*)alloc((size_t)FOUT * FIN * 2);   // 64 KB

  k_wsplit      <<<32, 256, 0, stream>>>(W, Wth, Wtl);
  k_gemm        <<<ROWS / 32, 256, 0, stream>>>(h, Wth, Wtl, ai, aj, Wh, sI, sJ);
  k_rank_scatter<<<BATCH * 64, 256, 0, stream>>>(sJ, sortedS, perm, e12);
  k_fuseout     <<<BATCH * 32, 512, 0, stream>>>(sortedS, sI, e12, Wh, perm, out);
}

// Round 9
// 107.066 us; speedup vs baseline: 2.8315x; 1.0251x over previous
//
#include <hip/hip_runtime.h>
#include <hip/hip_bf16.h>

#define BATCH 8
#define NN 2048
#define FIN 256
#define FOUT 128
#define ROWS (BATCH*NN)
#define NP1 (NN+1)
#define SEGS 128         // row segments per batch in k_fuseout
#define SLEN (NN/SEGS)   // 16 rows per segment

typedef __attribute__((ext_vector_type(8))) __bf16 bf16x8;
typedef __attribute__((ext_vector_type(4))) float f32x4;
typedef __attribute__((ext_vector_type(8))) unsigned short ushort8_t;

__device__ __forceinline__ unsigned pack2(float a, float b){
  __hip_bfloat16 x = __float2bfloat16(a), y = __float2bfloat16(b);
  unsigned short ux = *(unsigned short*)&x, uy = *(unsigned short*)&y;
  return ((unsigned)uy << 16) | (unsigned)ux;
}
__device__ __forceinline__ float lo2f(unsigned u){ union{unsigned v;float f;}c; c.v = u << 16; return c.f; }
__device__ __forceinline__ float hi2f(unsigned u){ union{unsigned v;float f;}c; c.v = u & 0xffff0000u; return c.f; }

// split x into bf16 hi + bf16 lo (x ≈ hi + lo, error ~2^-17 relative)
__device__ __forceinline__ void bsplit(float x, unsigned short& hu, unsigned short& lu){
  __hip_bfloat16 hb = __float2bfloat16(x);
  hu = *(unsigned short*)&hb;
  union{unsigned u; float f;} hf; hf.u = (unsigned)hu << 16;
  __hip_bfloat16 lb = __float2bfloat16(x - hf.f);
  lu = *(unsigned short*)&lb;
}

// ---------------- K0: split W -> transposed bf16 hi/lo [col][k] (r4-proven) ----
__global__ __launch_bounds__(256) void k_wsplit(const float* __restrict__ W,
                                                unsigned short* __restrict__ Wth,
                                                unsigned short* __restrict__ Wtl){
  const int gid = blockIdx.x * 256 + threadIdx.x;   // 0..8191
  const int k = gid >> 5, c4 = (gid & 31) * 4;
  float4 v = *(const float4*)&W[(size_t)k * FOUT + c4];
  float xs[4] = {v.x, v.y, v.z, v.w};
  #pragma unroll
  for (int i = 0; i < 4; i++){
    unsigned short hu, lu;
    bsplit(xs[i], hu, lu);
    Wth[(size_t)(c4 + i) * FIN + k] = hu;
    Wtl[(size_t)(c4 + i) * FIN + k] = lu;
  }
}

// ---------------- K1: MFMA split-bf16 Wh = h @ W + fused s_i/s_j (r8-proven) ----
// Wh stored COLUMN-BLOCKED [b][og(32)][row(NN)][4].
__global__ __launch_bounds__(256) void k_gemm(const float* __restrict__ h,
                                              const unsigned short* __restrict__ Wth,
                                              const unsigned short* __restrict__ Wtl,
                                              const float* __restrict__ ai,
                                              const float* __restrict__ aj,
                                              float* __restrict__ Wh,
                                              float* __restrict__ sI,
                                              float* __restrict__ sJ){
  __shared__ unsigned short Ah[32*40], Al[32*40];     // [row][k] pad 40 ushort (80 B)
  __shared__ unsigned short Bh[128*40], Bl[128*40];   // [col][k] pad 40
  __shared__ float spI[2][32], spJ[2][32];
  const int t = threadIdx.x;
  const int rbase = blockIdx.x * 32;
  const int b = rbase >> 11;
  const int brow0 = rbase & (NN - 1);
  const int w = t >> 6, l = t & 63;
  const int g = w & 1, cg = w >> 1;       // row-half, col-group(64)
  const int lr = l & 15, lq = l >> 4;     // M/N low index, k-quarter
  const int sar = t >> 3, sak = (t & 7) * 4;   // A staging: row, k-off (4 floats)
  const int sbc = t >> 1, sbh = (t & 1) * 16;  // B staging: col, k-half

  f32x4 acc[4];
  #pragma unroll
  for (int ct = 0; ct < 4; ct++) acc[ct] = (f32x4){0.f, 0.f, 0.f, 0.f};

  for (int k0 = 0; k0 < FIN; k0 += 32){
    {
      float4 hv = *(const float4*)&h[(size_t)(rbase + sar) * FIN + k0 + sak];
      float xs[4] = {hv.x, hv.y, hv.z, hv.w};
      ushort4 hh, ll;
      unsigned short hu, lu;
      bsplit(xs[0], hu, lu); hh.x = hu; ll.x = lu;
      bsplit(xs[1], hu, lu); hh.y = hu; ll.y = lu;
      bsplit(xs[2], hu, lu); hh.z = hu; ll.z = lu;
      bsplit(xs[3], hu, lu); hh.w = hu; ll.w = lu;
      *(ushort4*)&Ah[sar * 40 + sak] = hh;
      *(ushort4*)&Al[sar * 40 + sak] = ll;
    }
    {
      const size_t gb = (size_t)sbc * FIN + k0 + sbh;
      ushort8_t b0 = *(const ushort8_t*)&Wth[gb];
      ushort8_t b1 = *(const ushort8_t*)&Wth[gb + 8];
      ushort8_t c0 = *(const ushort8_t*)&Wtl[gb];
      ushort8_t c1 = *(const ushort8_t*)&Wtl[gb + 8];
      *(ushort8_t*)&Bh[sbc * 40 + sbh]     = b0;
      *(ushort8_t*)&Bh[sbc * 40 + sbh + 8] = b1;
      *(ushort8_t*)&Bl[sbc * 40 + sbh]     = c0;
      *(ushort8_t*)&Bl[sbc * 40 + sbh + 8] = c1;
    }
    __syncthreads();
    const bf16x8 avh = __builtin_bit_cast(bf16x8, *(const ushort8_t*)&Ah[(g*16 + lr)*40 + lq*8]);
    const bf16x8 avl = __builtin_bit_cast(bf16x8, *(const ushort8_t*)&Al[(g*16 + lr)*40 + lq*8]);
    #pragma unroll
    for (int ct = 0; ct < 4; ct++){
      const int col = cg*64 + ct*16 + lr;
      const bf16x8 bvh = __builtin_bit_cast(bf16x8, *(const ushort8_t*)&Bh[col*40 + lq*8]);
      const bf16x8 bvl = __builtin_bit_cast(bf16x8, *(const ushort8_t*)&Bl[col*40 + lq*8]);
      acc[ct] = __builtin_amdgcn_mfma_f32_16x16x32_bf16(avh, bvh, acc[ct], 0, 0, 0);
      acc[ct] = __builtin_amdgcn_mfma_f32_16x16x32_bf16(avh, bvl, acc[ct], 0, 0, 0);
      acc[ct] = __builtin_amdgcn_mfma_f32_16x16x32_bf16(avl, bvh, acc[ct], 0, 0, 0);
    }
    __syncthreads();
  }
  float pi[4] = {0.f,0.f,0.f,0.f}, pj[4] = {0.f,0.f,0.f,0.f};
  #pragma unroll
  for (int ct = 0; ct < 4; ct++){
    const int col = cg*64 + ct*16 + lr;
    const int og = col >> 2, ol2 = col & 3;
    const float fai = ai[col], faj = aj[col];
    const size_t obase = ((size_t)(b * 32 + og) * NN + brow0 + g*16 + lq*4) * 4 + ol2;
    #pragma unroll
    for (int q = 0; q < 4; q++){
      const float val = acc[ct][q];
      Wh[obase + (size_t)q * 4] = val;
      pi[q] = fmaf(val, fai, pi[q]);
      pj[q] = fmaf(val, faj, pj[q]);
    }
  }
  #pragma unroll
  for (int q = 0; q < 4; q++){
    #pragma unroll
    for (int m = 1; m < 16; m <<= 1){
      pi[q] += __shfl_xor(pi[q], m);
      pj[q] += __shfl_xor(pj[q], m);
    }
  }
  if (lr == 0){
    #pragma unroll
    for (int q = 0; q < 4; q++){
      spI[cg][g*16 + lq*4 + q] = pi[q];
      spJ[cg][g*16 + lq*4 + q] = pj[q];
    }
  }
  __syncthreads();
  if (t < 32){
    sI[rbase + t] = spI[0][t] + spI[1][t];
    sJ[rbase + t] = spJ[0][t] + spJ[1][t];
  }
}

// ---------------- K2: rank + scatter + k-count ----------
// As r5/r8 plus: counts k[row] = #{j: sJ[j] <= -sI[row]} for its 32 rows against
// the LDS-resident sJ (bit-identical to the old binary-search result), emitting
// skP[row] = (sI, k). Scatter output packed pe4[rank] = (e1, e2, perm, -).
__global__ __launch_bounds__(256) void k_rank_scatter(const float* __restrict__ sJ,
                                                      const float* __restrict__ sI,
                                                      float4* __restrict__ pe4,
                                                      float2* __restrict__ skP){
  const int b = blockIdx.x >> 6;        // 64 blocks per batch
  const int jc = blockIdx.x & 63;       // 32 j's per block
  __shared__ float v[NN];               // 8 KB
  __shared__ int partialR[8][32];
  __shared__ int partialC[8][32];
  const int t = threadIdx.x;
  const float* sj = sJ + b * NN;
  #pragma unroll
  for (int u = 0; u < 2; u++)
    ((float4*)v)[t + u * 256] = ((const float4*)sj)[t + u * 256];
  const int jj = t & 31, qq = t >> 5;
  const int j = jc * 32 + jj;
  const float x = sj[j];
  const float key = -sI[b * NN + j];
  __syncthreads();
  const int q0 = qq * 256;
  int r = 0, c = 0;
  #pragma unroll 8
  for (int q4 = 0; q4 < 64; q4++){
    const int q = q0 + q4 * 4;
    float4 y = *(const float4*)&v[q];
    r += (y.x < x) || (y.x == x && (q + 0) < j);
    r += (y.y < x) || (y.y == x && (q + 1) < j);
    r += (y.z < x) || (y.z == x && (q + 2) < j);
    r += (y.w < x) || (y.w == x && (q + 3) < j);
    c += (y.x <= key);
    c += (y.y <= key);
    c += (y.z <= key);
    c += (y.w <= key);
  }
  partialR[qq][jj] = r;
  partialC[qq][jj] = c;
  __syncthreads();
  if (t < 32){
    int R = 0, C = 0;
    #pragma unroll
    for (int q8 = 0; q8 < 8; q8++){ R += partialR[q8][t]; C += partialC[q8][t]; }
    const int myj = jc * 32 + t;
    const float xx = v[myj];
    pe4[b * NN + R] = make_float4(expf(xx), expf(0.01f * xx), __int_as_float(myj), 0.f);
    skP[b * NN + myj] = make_float2(sI[b * NN + myj], __int_as_float(C));
  }
}

// ---------------- K3: fully-fused column scan + epilogue (search-free) ----------
// Block (b, og) owns 4 output columns; Wh slice private/contiguous (32 KB).
// Wave-shfl seg scan (1 barrier). Epilogue uses precomputed k from skP
// (no ssL, no binary search).
__global__ __launch_bounds__(512) void k_fuseout(const float2* __restrict__ skP,
                                                 const float4* __restrict__ pe4,
                                                 const float* __restrict__ Wh,
                                                 float* __restrict__ out){
  __shared__ float2   abL[NP1];         // 16392 B scalar e1/e2 prefix
  __shared__ unsigned PL[NP1][4];       // 32784 B packed P, own 4 cols
  __shared__ float wtP1[8][4], wtP2[8][4], wtS1[8], wtS2[8];  // wave totals
  const int bc = blockIdx.x;            // 0..255
  const int b = bc >> 5;                // 32 blocks per batch
  const int og = bc & 31;               // 4 output cols each
  const int t = threadIdx.x;
  const int ol = t & 3;
  const int seg = t >> 2;               // 0..127
  const int r0 = seg * SLEN;
  const int wv = t >> 6, wl = t & 63;   // wave id / lane (seg = wv*16 + (wl>>2))

  const float4* pe  = pe4 + b * NN;
  const float*  whb = Wh + (size_t)(b * 32 + og) * NN * 4;   // private 32 KB slice
  float w[SLEN], ex[SLEN], ey[SLEN];
  float t1 = 0.f, t2 = 0.f, s1 = 0.f, s2 = 0.f;
  #pragma unroll
  for (int r = 0; r < SLEN; r++){       // full unroll: static reg indices
    const float4 u = pe[r0 + r];
    const int pmr = __float_as_int(u.z);
    w[r] = whb[(size_t)pmr * 4 + ol];
    ex[r] = u.x; ey[r] = u.y;
    t1 = fmaf(u.x, w[r], t1);
    t2 = fmaf(u.y, w[r], t2);
    s1 += u.x; s2 += u.y;
  }
  // ---- wave-level inclusive scan over segs ----
  float c1 = t1, c2 = t2, cs1 = s1, cs2 = s2;
  #pragma unroll
  for (int d = 1; d < 16; d <<= 1){
    const float u1 = __shfl_up(c1, d * 4);
    const float u2 = __shfl_up(c2, d * 4);
    const float u3 = __shfl_up(cs1, d * 4);
    const float u4 = __shfl_up(cs2, d * 4);
    if ((wl >> 2) >= d){ c1 += u1; c2 += u2; cs1 += u3; cs2 += u4; }
  }
  if ((wl >> 2) == 15){                 // last seg of wave: wave totals
    wtP1[wv][ol] = c1; wtP2[wv][ol] = c2;
    if (ol == 0){ wtS1[wv] = cs1; wtS2[wv] = cs2; }
  }
  __syncthreads();
  for (int ww = 0; ww < wv; ww++){      // cross-wave exclusive fixup (wave-uniform)
    c1 += wtP1[ww][ol]; c2 += wtP2[ww][ol];
    cs1 += wtS1[ww];    cs2 += wtS2[ww];
  }
  float acc1 = c1 - t1;                 // exclusive offsets
  float acc2 = c2 - t2;
  if (seg == 0){
    PL[0][ol] = 0u;
    if (ol == 0) abL[0] = make_float2(0.f, 0.f);
  }
  {
    float offs1 = 0.f, offs2 = 0.f;
    if (ol == 0){ offs1 = cs1 - s1; offs2 = cs2 - s2; }
    float run1 = 0.f, run2 = 0.f;
    #pragma unroll
    for (int r = 0; r < SLEN; r++){
      acc1 = fmaf(ex[r], w[r], acc1);
      acc2 = fmaf(ey[r], w[r], acc2);
      PL[r0 + r + 1][ol] = pack2(acc1, acc2);
      if (ol == 0){
        run1 += ex[r]; run2 += ey[r];
        abL[r0 + r + 1] = make_float2(offs1 + run1, offs2 + run2);
      }
    }
  }
  __syncthreads();
  // ---- epilogue: 16 rows per thread, k precomputed (no search) ----
  const int tg = t >> 2;                // 0..127; rows tg + u*128
  const float2* skb = skP + b * NN;
  const float2 vT = abL[NN];
  const unsigned uTp = PL[NN][ol];
  #pragma unroll
  for (int u = 0; u < 16; u++){
    const int row = tg + u * 128;
    const float2 sk = skb[row];
    const float s = sk.x;
    const int k = __float_as_int(sk.y);
    const float w1 = expf(s), w2 = expf(0.01f * s);
    const float2 vk = abL[k];
    const float inv = 1.0f / (w1 * (vT.x - vk.x) + w2 * vk.y);
    const unsigned uk = PL[k][ol];
    const float num = w1 * (lo2f(uTp) - lo2f(uk)) + w2 * hi2f(uk);
    out[(size_t)(b * NN + row) * FOUT + og * 4 + ol] = num * inv;
  }
}

extern "C" void kernel_launch(void* const* d_in, const int* in_sizes, int n_in,
                              void* d_out, int out_size, void* d_ws, size_t ws_size,
                              hipStream_t stream){
  const float* h  = (const float*)d_in[0];
  const float* W  = (const float*)d_in[1];
  const float* ai = (const float*)d_in[2];
  const float* aj = (const float*)d_in[3];
  float* out = (float*)d_out;

  char* ws = (char*)d_ws;
  size_t off = 0;
  auto alloc = [&](size_t bytes) -> void* {
    void* p = ws + off;
    off += (bytes + 255) & ~(size_t)255;
    return p;
  };
  float*          Wh   = (float*)   alloc((size_t)ROWS * FOUT * 4);        // 8 MB (blocked)
  float*          sI   = (float*)   alloc((size_t)ROWS * 4);
  float*          sJ   = (float*)   alloc((size_t)ROWS * 4);
  float4*         pe4  = (float4*)  alloc((size_t)BATCH * NN * 16);        // 256 KB
  float2*         skP  = (float2*)  alloc((size_t)BATCH * NN * 8);         // 128 KB
  unsigned short* Wth  = (unsigned short*)alloc((size_t)FOUT * FIN * 2);   // 64 KB
  unsigned short* Wtl  = (unsigned short*)alloc((size_t)FOUT * FIN * 2);   // 64 KB

  k_wsplit      <<<32, 256, 0, stream>>>(W, Wth, Wtl);
  k_gemm        <<<ROWS / 32, 256, 0, stream>>>(h, Wth, Wtl, ai, aj, Wh, sI, sJ);
  k_rank_scatter<<<BATCH * 64, 256, 0, stream>>>(sJ, sI, pe4, skP);
  k_fuseout     <<<BATCH * 32, 512, 0, stream>>>(skP, pe4, Wh, out);
}

// Round 10
// 104.915 us; speedup vs baseline: 2.8895x; 1.0205x over previous
//
#include <hip/hip_runtime.h>
#include <hip/hip_bf16.h>

#define BATCH 8
#define NN 2048
#define FIN 256
#define FOUT 128
#define ROWS (BATCH*NN)
#define NP1 (NN+1)
#define SEGS 128         // row segments per batch in k_fuseout
#define SLEN (NN/SEGS)   // 16 rows per segment

typedef __attribute__((ext_vector_type(8))) __bf16 bf16x8;
typedef __attribute__((ext_vector_type(4))) float f32x4;
typedef __attribute__((ext_vector_type(8))) unsigned short ushort8_t;

__device__ __forceinline__ unsigned pack2(float a, float b){
  __hip_bfloat16 x = __float2bfloat16(a), y = __float2bfloat16(b);
  unsigned short ux = *(unsigned short*)&x, uy = *(unsigned short*)&y;
  return ((unsigned)uy << 16) | (unsigned)ux;
}
__device__ __forceinline__ float lo2f(unsigned u){ union{unsigned v;float f;}c; c.v = u << 16; return c.f; }
__device__ __forceinline__ float hi2f(unsigned u){ union{unsigned v;float f;}c; c.v = u & 0xffff0000u; return c.f; }

// split x into bf16 hi + bf16 lo (x ≈ hi + lo, error ~2^-17 relative)
__device__ __forceinline__ void bsplit(float x, unsigned short& hu, unsigned short& lu){
  __hip_bfloat16 hb = __float2bfloat16(x);
  hu = *(unsigned short*)&hb;
  union{unsigned u; float f;} hf; hf.u = (unsigned)hu << 16;
  __hip_bfloat16 lb = __float2bfloat16(x - hf.f);
  lu = *(unsigned short*)&lb;
}

// ---------------- K1: MFMA split-bf16 Wh = h @ W + fused s_i/s_j ----------------
// Wh stored COLUMN-BLOCKED [b][og(32)][row(NN)][4].
// W split hi/lo ON THE FLY during B staging (k_wsplit folded in): thread loads
// 16 fp32 of W column (sbc) for k0+sbh..+15 (L2-hot, 2x128B segs/instr), splits
// in regs, writes the IDENTICAL ushort8 hi/lo LDS stores as before.
__global__ __launch_bounds__(256) void k_gemm(const float* __restrict__ h,
                                              const float* __restrict__ W,
                                              const float* __restrict__ ai,
                                              const float* __restrict__ aj,
                                              float* __restrict__ Wh,
                                              float* __restrict__ sI,
                                              float* __restrict__ sJ){
  __shared__ unsigned short Ah[32*40], Al[32*40];     // [row][k] pad 40 ushort (80 B)
  __shared__ unsigned short Bh[128*40], Bl[128*40];   // [col][k] pad 40
  __shared__ float spI[2][32], spJ[2][32];
  const int t = threadIdx.x;
  const int rbase = blockIdx.x * 32;
  const int b = rbase >> 11;
  const int brow0 = rbase & (NN - 1);
  const int w = t >> 6, l = t & 63;
  const int g = w & 1, cg = w >> 1;       // row-half, col-group(64)
  const int lr = l & 15, lq = l >> 4;     // M/N low index, k-quarter
  const int sar = t >> 3, sak = (t & 7) * 4;   // A staging: row, k-off (4 floats)
  const int sbc = t >> 1, sbh = (t & 1) * 16;  // B staging: col, k-half

  f32x4 acc[4];
  #pragma unroll
  for (int ct = 0; ct < 4; ct++) acc[ct] = (f32x4){0.f, 0.f, 0.f, 0.f};

  for (int k0 = 0; k0 < FIN; k0 += 32){
    {
      float4 hv = *(const float4*)&h[(size_t)(rbase + sar) * FIN + k0 + sak];
      float xs[4] = {hv.x, hv.y, hv.z, hv.w};
      ushort4 hh, ll;
      unsigned short hu, lu;
      bsplit(xs[0], hu, lu); hh.x = hu; ll.x = lu;
      bsplit(xs[1], hu, lu); hh.y = hu; ll.y = lu;
      bsplit(xs[2], hu, lu); hh.z = hu; ll.z = lu;
      bsplit(xs[3], hu, lu); hh.w = hu; ll.w = lu;
      *(ushort4*)&Ah[sar * 40 + sak] = hh;
      *(ushort4*)&Al[sar * 40 + sak] = ll;
    }
    {
      // on-the-fly W split: col sbc, k = k0+sbh .. k0+sbh+15
      float wv[16];
      #pragma unroll
      for (int i = 0; i < 16; i++)
        wv[i] = W[(size_t)(k0 + sbh + i) * FOUT + sbc];
      unsigned short h8[16], l8[16];
      #pragma unroll
      for (int i = 0; i < 16; i++) bsplit(wv[i], h8[i], l8[i]);
      *(ushort8_t*)&Bh[sbc * 40 + sbh]     = *(ushort8_t*)&h8[0];
      *(ushort8_t*)&Bh[sbc * 40 + sbh + 8] = *(ushort8_t*)&h8[8];
      *(ushort8_t*)&Bl[sbc * 40 + sbh]     = *(ushort8_t*)&l8[0];
      *(ushort8_t*)&Bl[sbc * 40 + sbh + 8] = *(ushort8_t*)&l8[8];
    }
    __syncthreads();
    const bf16x8 avh = __builtin_bit_cast(bf16x8, *(const ushort8_t*)&Ah[(g*16 + lr)*40 + lq*8]);
    const bf16x8 avl = __builtin_bit_cast(bf16x8, *(const ushort8_t*)&Al[(g*16 + lr)*40 + lq*8]);
    #pragma unroll
    for (int ct = 0; ct < 4; ct++){
      const int col = cg*64 + ct*16 + lr;
      const bf16x8 bvh = __builtin_bit_cast(bf16x8, *(const ushort8_t*)&Bh[col*40 + lq*8]);
      const bf16x8 bvl = __builtin_bit_cast(bf16x8, *(const ushort8_t*)&Bl[col*40 + lq*8]);
      acc[ct] = __builtin_amdgcn_mfma_f32_16x16x32_bf16(avh, bvh, acc[ct], 0, 0, 0);
      acc[ct] = __builtin_amdgcn_mfma_f32_16x16x32_bf16(avh, bvl, acc[ct], 0, 0, 0);
      acc[ct] = __builtin_amdgcn_mfma_f32_16x16x32_bf16(avl, bvh, acc[ct], 0, 0, 0);
    }
    __syncthreads();
  }
  float pi[4] = {0.f,0.f,0.f,0.f}, pj[4] = {0.f,0.f,0.f,0.f};
  #pragma unroll
  for (int ct = 0; ct < 4; ct++){
    const int col = cg*64 + ct*16 + lr;
    const int og = col >> 2, ol2 = col & 3;
    const float fai = ai[col], faj = aj[col];
    const size_t obase = ((size_t)(b * 32 + og) * NN + brow0 + g*16 + lq*4) * 4 + ol2;
    #pragma unroll
    for (int q = 0; q < 4; q++){
      const float val = acc[ct][q];
      Wh[obase + (size_t)q * 4] = val;
      pi[q] = fmaf(val, fai, pi[q]);
      pj[q] = fmaf(val, faj, pj[q]);
    }
  }
  #pragma unroll
  for (int q = 0; q < 4; q++){
    #pragma unroll
    for (int m = 1; m < 16; m <<= 1){
      pi[q] += __shfl_xor(pi[q], m);
      pj[q] += __shfl_xor(pj[q], m);
    }
  }
  if (lr == 0){
    #pragma unroll
    for (int q = 0; q < 4; q++){
      spI[cg][g*16 + lq*4 + q] = pi[q];
      spJ[cg][g*16 + lq*4 + q] = pj[q];
    }
  }
  __syncthreads();
  if (t < 32){
    sI[rbase + t] = spI[0][t] + spI[1][t];
    sJ[rbase + t] = spJ[0][t] + spJ[1][t];
  }
}

// ---------------- K2: rank + scatter + k-count (r9-proven) ----------
// Counts k[row] = #{j: sJ[j] <= -sI[row]} (== old binary-search result) and
// emits skP[row] = (sI, k); scatter packed pe4[rank] = (e1, e2, perm, -).
__global__ __launch_bounds__(256) void k_rank_scatter(const float* __restrict__ sJ,
                                                      const float* __restrict__ sI,
                                                      float4* __restrict__ pe4,
                                                      float2* __restrict__ skP){
  const int b = blockIdx.x >> 6;        // 64 blocks per batch
  const int jc = blockIdx.x & 63;       // 32 j's per block
  __shared__ float v[NN];               // 8 KB
  __shared__ int partialR[8][32];
  __shared__ int partialC[8][32];
  const int t = threadIdx.x;
  const float* sj = sJ + b * NN;
  #pragma unroll
  for (int u = 0; u < 2; u++)
    ((float4*)v)[t + u * 256] = ((const float4*)sj)[t + u * 256];
  const int jj = t & 31, qq = t >> 5;
  const int j = jc * 32 + jj;
  const float x = sj[j];
  const float sIv = sI[b * NN + j];
  const float key = -sIv;
  __syncthreads();
  const int q0 = qq * 256;
  int r = 0, c = 0;
  #pragma unroll 8
  for (int q4 = 0; q4 < 64; q4++){
    const int q = q0 + q4 * 4;
    float4 y = *(const float4*)&v[q];
    r += (y.x < x) || (y.x == x && (q + 0) < j);
    r += (y.y < x) || (y.y == x && (q + 1) < j);
    r += (y.z < x) || (y.z == x && (q + 2) < j);
    r += (y.w < x) || (y.w == x && (q + 3) < j);
    c += (y.x <= key);
    c += (y.y <= key);
    c += (y.z <= key);
    c += (y.w <= key);
  }
  partialR[qq][jj] = r;
  partialC[qq][jj] = c;
  __syncthreads();
  if (t < 32){
    int R = 0, C = 0;
    #pragma unroll
    for (int q8 = 0; q8 < 8; q8++){ R += partialR[q8][t]; C += partialC[q8][t]; }
    const int myj = jc * 32 + t;      // == this thread's j (qq==0, jj==t)
    const float xx = v[myj];
    pe4[b * NN + R] = make_float4(expf(xx), expf(0.01f * xx), __int_as_float(myj), 0.f);
    skP[b * NN + myj] = make_float2(sIv, __int_as_float(C));
  }
}

// ---------------- K3: fully-fused column scan + epilogue (r9-proven) ----------
__global__ __launch_bounds__(512) void k_fuseout(const float2* __restrict__ skP,
                                                 const float4* __restrict__ pe4,
                                                 const float* __restrict__ Wh,
                                                 float* __restrict__ out){
  __shared__ float2   abL[NP1];         // 16392 B scalar e1/e2 prefix
  __shared__ unsigned PL[NP1][4];       // 32784 B packed P, own 4 cols
  __shared__ float wtP1[8][4], wtP2[8][4], wtS1[8], wtS2[8];  // wave totals
  const int bc = blockIdx.x;            // 0..255
  const int b = bc >> 5;                // 32 blocks per batch
  const int og = bc & 31;               // 4 output cols each
  const int t = threadIdx.x;
  const int ol = t & 3;
  const int seg = t >> 2;               // 0..127
  const int r0 = seg * SLEN;
  const int wv = t >> 6, wl = t & 63;   // wave id / lane (seg = wv*16 + (wl>>2))

  const float4* pe  = pe4 + b * NN;
  const float*  whb = Wh + (size_t)(b * 32 + og) * NN * 4;   // private 32 KB slice
  float w[SLEN], ex[SLEN], ey[SLEN];
  float t1 = 0.f, t2 = 0.f, s1 = 0.f, s2 = 0.f;
  #pragma unroll
  for (int r = 0; r < SLEN; r++){       // full unroll: static reg indices
    const float4 u = pe[r0 + r];
    const int pmr = __float_as_int(u.z);
    w[r] = whb[(size_t)pmr * 4 + ol];
    ex[r] = u.x; ey[r] = u.y;
    t1 = fmaf(u.x, w[r], t1);
    t2 = fmaf(u.y, w[r], t2);
    s1 += u.x; s2 += u.y;
  }
  // ---- wave-level inclusive scan over segs ----
  float c1 = t1, c2 = t2, cs1 = s1, cs2 = s2;
  #pragma unroll
  for (int d = 1; d < 16; d <<= 1){
    const float u1 = __shfl_up(c1, d * 4);
    const float u2 = __shfl_up(c2, d * 4);
    const float u3 = __shfl_up(cs1, d * 4);
    const float u4 = __shfl_up(cs2, d * 4);
    if ((wl >> 2) >= d){ c1 += u1; c2 += u2; cs1 += u3; cs2 += u4; }
  }
  if ((wl >> 2) == 15){                 // last seg of wave: wave totals
    wtP1[wv][ol] = c1; wtP2[wv][ol] = c2;
    if (ol == 0){ wtS1[wv] = cs1; wtS2[wv] = cs2; }
  }
  __syncthreads();
  for (int ww = 0; ww < wv; ww++){      // cross-wave exclusive fixup (wave-uniform)
    c1 += wtP1[ww][ol]; c2 += wtP2[ww][ol];
    cs1 += wtS1[ww];    cs2 += wtS2[ww];
  }
  float acc1 = c1 - t1;                 // exclusive offsets
  float acc2 = c2 - t2;
  if (seg == 0){
    PL[0][ol] = 0u;
    if (ol == 0) abL[0] = make_float2(0.f, 0.f);
  }
  {
    float offs1 = 0.f, offs2 = 0.f;
    if (ol == 0){ offs1 = cs1 - s1; offs2 = cs2 - s2; }
    float run1 = 0.f, run2 = 0.f;
    #pragma unroll
    for (int r = 0; r < SLEN; r++){
      acc1 = fmaf(ex[r], w[r], acc1);
      acc2 = fmaf(ey[r], w[r], acc2);
      PL[r0 + r + 1][ol] = pack2(acc1, acc2);
      if (ol == 0){
        run1 += ex[r]; run2 += ey[r];
        abL[r0 + r + 1] = make_float2(offs1 + run1, offs2 + run2);
      }
    }
  }
  __syncthreads();
  // ---- epilogue: 16 rows per thread, k precomputed (no search) ----
  const int tg = t >> 2;                // 0..127; rows tg + u*128
  const float2* skb = skP + b * NN;
  const float2 vT = abL[NN];
  const unsigned uTp = PL[NN][ol];
  #pragma unroll
  for (int u = 0; u < 16; u++){
    const int row = tg + u * 128;
    const float2 sk = skb[row];
    const float s = sk.x;
    const int k = __float_as_int(sk.y);
    const float w1 = expf(s), w2 = expf(0.01f * s);
    const float2 vk = abL[k];
    const float inv = 1.0f / (w1 * (vT.x - vk.x) + w2 * vk.y);
    const unsigned uk = PL[k][ol];
    const float num = w1 * (lo2f(uTp) - lo2f(uk)) + w2 * hi2f(uk);
    out[(size_t)(b * NN + row) * FOUT + og * 4 + ol] = num * inv;
  }
}

extern "C" void kernel_launch(void* const* d_in, const int* in_sizes, int n_in,
                              void* d_out, int out_size, void* d_ws, size_t ws_size,
                              hipStream_t stream){
  const float* h  = (const float*)d_in[0];
  const float* W  = (const float*)d_in[1];
  const float* ai = (const float*)d_in[2];
  const float* aj = (const float*)d_in[3];
  float* out = (float*)d_out;

  char* ws = (char*)d_ws;
  size_t off = 0;
  auto alloc = [&](size_t bytes) -> void* {
    void* p = ws + off;
    off += (bytes + 255) & ~(size_t)255;
    return p;
  };
  float*   Wh  = (float*)  alloc((size_t)ROWS * FOUT * 4);   // 8 MB (blocked)
  float*   sI  = (float*)  alloc((size_t)ROWS * 4);
  float*   sJ  = (float*)  alloc((size_t)ROWS * 4);
  float4*  pe4 = (float4*) alloc((size_t)BATCH * NN * 16);   // 256 KB
  float2*  skP = (float2*) alloc((size_t)BATCH * NN * 8);    // 128 KB

  k_gemm        <<<ROWS / 32, 256, 0, stream>>>(h, W, ai, aj, Wh, sI, sJ);
  k_rank_scatter<<<BATCH * 64, 256, 0, stream>>>(sJ, sI, pe4, skP);
  k_fuseout     <<<BATCH * 32, 512, 0, stream>>>(skP, pe4, Wh, out);
}